// Round 7
// baseline (632.237 us; speedup 1.0000x reference)
//
#include <hip/hip_runtime.h>
#include <hip/hip_fp16.h>
#include <cstdint>

#define DH 64
#define EPSV 1e-5f
#define NSHARD 8

__device__ __forceinline__ float atomAddF(float* p, float v) {
  return unsafeAtomicAdd(p, v);
}

__global__ void k_fill(float* __restrict__ p, float v, size_t n) {
  size_t i = blockIdx.x * (size_t)blockDim.x + threadIdx.x;
  if (i < n) p[i] = v;
}

// packed sharded histogram: one u64 atomic per edge.
// bits[40:63] = count, bits[0:39] = fixed-point (2^-24) sum of edge weights.
__global__ void k_hist(const int* __restrict__ dst, const float* __restrict__ ew,
                       unsigned long long* __restrict__ shard, int N_, int E_) {
  int e = blockIdx.x * blockDim.x + threadIdx.x;
  if (e < E_) {
    int q = dst[e];
    unsigned long long v =
        (1ull << 40) | (unsigned long long)(unsigned)(ew[e] * 16777216.0f);
    atomicAdd(&shard[(size_t)(blockIdx.x & (NSHARD - 1)) * N_ + q], v);
  }
}

// reduce shards -> cnt, dinv, sc  (deg includes +1 self-loop)
__global__ void k_redhist(const unsigned long long* __restrict__ shard,
                          int* __restrict__ cnt, float* __restrict__ dinv,
                          float* __restrict__ sc, int N_) {
  int i = blockIdx.x * blockDim.x + threadIdx.x;
  if (i < N_) {
    unsigned long long t = 0;
#pragma unroll
    for (int s = 0; s < NSHARD; ++s) t += shard[(size_t)s * N_ + i];
    float deg = 1.0f + (float)(t & 0xFFFFFFFFFFull) * (1.0f / 16777216.0f);
    cnt[i] = (int)(t >> 40);
    dinv[i] = rsqrtf(deg);
    sc[i] = 1.0f / deg;
  }
}

// ---- exclusive scan over n1 = N+1 values; value(i) = i<N ? pad8(cnt[i]) : 0 ----
__global__ __launch_bounds__(256) void k_scan1(const int* __restrict__ cnt,
                                               int* __restrict__ out,
                                               int* __restrict__ bsums,
                                               int N_, int n1) {
  __shared__ int sm[256];
  const int t = threadIdx.x;
  const int base = blockIdx.x * 1024 + t * 4;
  int v[4], lsum = 0;
#pragma unroll
  for (int j = 0; j < 4; ++j) {
    int i = base + j;
    v[j] = (i < N_) ? ((cnt[i] + 7) & ~7) : 0;   // pad rows to multiple of 8
    lsum += v[j];
  }
  sm[t] = lsum;
  __syncthreads();
  for (int o = 1; o < 256; o <<= 1) {
    int x = (t >= o) ? sm[t - o] : 0;
    __syncthreads();
    if (t >= o) sm[t] += x;
    __syncthreads();
  }
  int run = sm[t] - lsum;
#pragma unroll
  for (int j = 0; j < 4; ++j) {
    int i = base + j;
    if (i < n1) out[i] = run;
    run += v[j];
  }
  if (t == 255) bsums[blockIdx.x] = sm[255];
}

__global__ __launch_bounds__(256) void k_scan2(int* __restrict__ bsums, int nb) {
  __shared__ int sm[256];
  int t = threadIdx.x;
  int v = (t < nb) ? bsums[t] : 0;
  sm[t] = v;
  __syncthreads();
  for (int o = 1; o < 256; o <<= 1) {
    int x = (t >= o) ? sm[t - o] : 0;
    __syncthreads();
    if (t >= o) sm[t] += x;
    __syncthreads();
  }
  if (t < nb) bsums[t] = sm[t] - v;
}

__global__ void k_scan3(int* __restrict__ out, const int* __restrict__ bsums, int n1) {
  int i = blockIdx.x * blockDim.x + threadIdx.x;
  if (i < n1) out[i] += bsums[i >> 10];
}

// write 0 (src=0, norm=0) into pad slots only
__global__ void k_padfill(const int* __restrict__ rowstart, const int* __restrict__ cnt,
                          unsigned* __restrict__ elist, int N_) {
  int i = blockIdx.x * blockDim.x + threadIdx.x;
  if (i < N_) {
    int p = rowstart[i] + cnt[i], pe = rowstart[i + 1];
    for (; p < pe; ++p) elist[p] = 0u;
  }
}

// CSR reorder, fusing norm computation. elist[p] = (fp16(norm) sans sign)<<17 | src
__global__ void k_reorder(const int* __restrict__ src, const int* __restrict__ dst,
                          const float* __restrict__ ew, const float* __restrict__ dinv,
                          const int* __restrict__ rowstart, int* __restrict__ cursor,
                          unsigned* __restrict__ elist, int E_) {
  int e = blockIdx.x * blockDim.x + threadIdx.x;
  if (e < E_) {
    int s = src[e], q = dst[e];
    float nm = ew[e] * dinv[s] * dinv[q];
    unsigned h15 = (unsigned)__half_as_ushort(__float2half(nm));  // sign bit 0
    int p = rowstart[q] + atomicAdd(&cursor[q], 1);
    elist[p] = (h15 << 17) | (unsigned)s;
  }
}

// graph boundary detection on sorted batch: gstart[g] for g in [0,G]
__global__ void k_gbound(const int* __restrict__ batch, int* __restrict__ gstart,
                         int N_, int G_) {
  int i = blockIdx.x * blockDim.x + threadIdx.x;
  if (i >= N_) return;
  int b = batch[i];
  if (i == 0) {
    for (int g = 0; g <= b; ++g) gstart[g] = 0;
  }
  int nb = (i + 1 < N_) ? batch[i + 1] : G_;
  for (int g = b + 1; g <= nb; ++g) gstart[g] = i + 1;
}

// C tile 128 rows x 64 cols, 256 threads, micro-tile 4x8 per thread.
// A dtype templated (fp32 layer0 / fp16 AGG later layers).
// Optionally applies BN(prev layer)+ReLU to A while loading. Writes fp16 H.
template <typename AT>
__global__ __launch_bounds__(256) void k_gemm(
    const AT* __restrict__ A, const float* __restrict__ W,
    const float* __restrict__ bias, const float* __restrict__ stats,
    const float* __restrict__ gam, const float* __restrict__ bet,
    __half* __restrict__ Hh, int n, int K, int fuse, float invN) {
  __shared__ float As[128][17];
  __shared__ float Bs[16][64];
  __shared__ float saL[DH], sbL[DH];
  const int tid = threadIdx.x;
  const int tx = tid & 7;
  const int ty = tid >> 3;
  const int r0 = blockIdx.x * 128;
  if (fuse && tid < DH) {
    float mean = stats[tid] * invN;
    float var = stats[DH + tid] * invN - mean * mean;
    float a = rsqrtf(var + EPSV) * gam[tid];
    saL[tid] = a;
    sbL[tid] = bet[tid] - mean * a;
  }
  if (fuse) __syncthreads();
  float acc[4][8] = {};
  for (int kc = 0; kc < K; kc += 16) {
    for (int idx = tid; idx < 128 * 16; idx += 256) {
      int r = idx >> 4, c = idx & 15;
      int gr = r0 + r, gc = kc + c;
      float v = (gr < n && gc < K) ? (float)A[(size_t)gr * K + gc] : 0.0f;
      if (fuse) v = fmaxf(v * saL[gc] + sbL[gc], 0.0f);
      As[r][c] = v;
    }
    for (int idx = tid; idx < 16 * 64; idx += 256) {
      int r = idx >> 6, c = idx & 63;
      int gr = kc + r;
      Bs[r][c] = (gr < K) ? W[gr * DH + c] : 0.0f;
    }
    __syncthreads();
#pragma unroll
    for (int kk = 0; kk < 16; ++kk) {
      float a[4], b[8];
#pragma unroll
      for (int i = 0; i < 4; ++i) a[i] = As[ty * 4 + i][kk];
#pragma unroll
      for (int j = 0; j < 8; ++j) b[j] = Bs[kk][tx * 8 + j];
#pragma unroll
      for (int i = 0; i < 4; ++i)
#pragma unroll
        for (int j = 0; j < 8; ++j) acc[i][j] += a[i] * b[j];
    }
    __syncthreads();
  }
#pragma unroll
  for (int i = 0; i < 4; ++i) {
    int gr = r0 + ty * 4 + i;
    if (gr < n) {
      float h[8];
#pragma unroll
      for (int j = 0; j < 8; ++j) h[j] = acc[i][j] + bias[tx * 8 + j];
      uint4 o;
      o.x = (unsigned)__half_as_ushort(__float2half(h[0])) |
            ((unsigned)__half_as_ushort(__float2half(h[1])) << 16);
      o.y = (unsigned)__half_as_ushort(__float2half(h[2])) |
            ((unsigned)__half_as_ushort(__float2half(h[3])) << 16);
      o.z = (unsigned)__half_as_ushort(__float2half(h[4])) |
            ((unsigned)__half_as_ushort(__float2half(h[5])) << 16);
      o.w = (unsigned)__half_as_ushort(__float2half(h[6])) |
            ((unsigned)__half_as_ushort(__float2half(h[7])) << 16);
      *reinterpret_cast<uint4*>(&Hh[(size_t)gr * DH + tx * 8]) = o;
    }
  }
}

// Pull aggregation: one wave per dst row (grid-stride), lane d = feature d.
// Rows padded to multiples of 8 edges -> tail-free, 8 gathers in flight.
// fp16 H operand, packed 4B elist, fp16 AGG out, fused fp32 BN stats.
__global__ __launch_bounds__(256) void k_gather(
    const unsigned* __restrict__ elist, const int* __restrict__ rowstart,
    const __half* __restrict__ Hh, const float* __restrict__ sc,
    __half* __restrict__ AGGh, float* __restrict__ stats, int n) {
  const int wid = threadIdx.x >> 6;
  const int d = threadIdx.x & 63;
  const int gw = blockIdx.x * 4 + wid;
  const int nw = gridDim.x * 4;
  float s = 0.f, ss = 0.f;
  for (int row = gw; row < n; row += nw) {
    int rs = rowstart[row], re = rowstart[row + 1];
    float acc = __half2float(Hh[(size_t)row * DH + d]) * sc[row];
    for (int i = rs; i < re; i += 8) {
      unsigned e[8];
#pragma unroll
      for (int j = 0; j < 8; ++j) e[j] = elist[i + j];
      float v[8];
#pragma unroll
      for (int j = 0; j < 8; ++j)
        v[j] = __half2float(Hh[(size_t)(e[j] & 0x1FFFFu) * DH + d]);
#pragma unroll
      for (int j = 0; j < 8; ++j) {
        float nm = __half2float(__ushort_as_half((unsigned short)(e[j] >> 17)));
        acc = fmaf(nm, v[j], acc);
      }
    }
    AGGh[(size_t)row * DH + d] = __float2half(acc);
    s += acc;
    ss += acc * acc;
  }
  __shared__ float sm[4][DH], sm2[4][DH];
  sm[wid][d] = s;
  sm2[wid][d] = ss;
  __syncthreads();
  if (threadIdx.x < DH) {
    float a = sm[0][d] + sm[1][d] + sm[2][d] + sm[3][d];
    float b = sm2[0][d] + sm2[1][d] + sm2[2][d] + sm2[3][d];
    atomAddF(&stats[d], a);
    atomAddF(&stats[DH + d], b);
  }
}

// fused BN+ReLU+mean-pool+head: one block per graph.
__global__ __launch_bounds__(256) void k_poolhead(
    const __half* __restrict__ AGGh, const float* __restrict__ stats,
    const float* __restrict__ gam, const float* __restrict__ bet,
    const float* __restrict__ ow, const int* __restrict__ gstart,
    const float* __restrict__ ob, float* __restrict__ out, float invN) {
  const int g = blockIdx.x;
  const int gs = gstart[g], ge = gstart[g + 1];
  const int wid = threadIdx.x >> 6;
  const int d = threadIdx.x & 63;
  float mean = stats[d] * invN;
  float var = stats[DH + d] * invN - mean * mean;
  float sa = rsqrtf(var + EPSV) * gam[d];
  float sb = bet[d] - mean * sa;
  const float w = ow[d];
  float acc = 0.f;
  for (int row = gs + wid; row < ge; row += 4)
    acc += fmaxf(__half2float(AGGh[(size_t)row * DH + d]) * sa + sb, 0.f) * w;
#pragma unroll
  for (int off = 32; off > 0; off >>= 1) acc += __shfl_down(acc, off, 64);
  __shared__ float sm[4];
  if (d == 0) sm[wid] = acc;
  __syncthreads();
  if (threadIdx.x == 0) {
    float s = sm[0] + sm[1] + sm[2] + sm[3];
    float cnt = (float)(ge - gs);
    out[g] = s / fmaxf(cnt, 1.0f) + ob[0];
  }
}

extern "C" void kernel_launch(void* const* d_in, const int* in_sizes, int n_in,
                              void* d_out, int out_size, void* d_ws, size_t ws_size,
                              hipStream_t stream) {
  const float* x    = (const float*)d_in[0];
  const int*   ei   = (const int*)d_in[1];
  const float* ew   = (const float*)d_in[2];
  const int*   batch= (const int*)d_in[3];
  const float* w0   = (const float*)d_in[4];
  const float* b0   = (const float*)d_in[5];
  const float* g0   = (const float*)d_in[6];
  const float* be0  = (const float*)d_in[7];
  const float* w1   = (const float*)d_in[8];
  const float* b1   = (const float*)d_in[9];
  const float* g1   = (const float*)d_in[10];
  const float* be1  = (const float*)d_in[11];
  const float* w2   = (const float*)d_in[12];
  const float* b2   = (const float*)d_in[13];
  const float* g2   = (const float*)d_in[14];
  const float* be2  = (const float*)d_in[15];
  const float* ow   = (const float*)d_in[16];
  const float* ob   = (const float*)d_in[17];

  const int N_  = in_sizes[3];
  const int E_  = in_sizes[2];
  const int DIN_= in_sizes[0] / N_;
  const int G_  = out_size;
  const int* srcIdx = ei;
  const int* dstIdx = ei + E_;
  const int n1 = N_ + 1;
  const size_t epad = (size_t)E_ + 7ull * N_;   // max padded edge slots

  float* ws = (float*)d_ws;
  size_t off = 0;
  unsigned* elist = (unsigned*)(ws + off); off += epad;
  unsigned long long* shard = (unsigned long long*)(ws + off); off += (size_t)2 * NSHARD * N_;
  float* dinv     = ws + off; off += N_;
  float* sc       = ws + off; off += N_;
  int*   cnt      = (int*)(ws + off); off += N_;
  int*   cursor   = (int*)(ws + off); off += N_;
  int*   rowstart = (int*)(ws + off); off += n1 + 1;
  int*   bsums    = (int*)(ws + off); off += 256;
  int*   gstart   = (int*)(ws + off); off += G_ + 1;
  __half* hhalf   = (__half*)(ws + off); off += (size_t)N_ * DH / 2;
  __half* aggh    = (__half*)(ws + off); off += (size_t)N_ * DH / 2;
  float* stats    = ws + off; off += 2 * DH;
  (void)ws_size; (void)n_in;

  // --- packed sharded histogram ---
  k_fill<<<(int)(((size_t)2 * NSHARD * N_ + 255) / 256), 256, 0, stream>>>(
      (float*)shard, 0.0f, (size_t)2 * NSHARD * N_);
  k_hist<<<(E_ + 255) / 256, 256, 0, stream>>>(dstIdx, ew, shard, N_, E_);
  k_redhist<<<(N_ + 255) / 256, 256, 0, stream>>>(shard, cnt, dinv, sc, N_);

  // --- exclusive scan padded cnt -> rowstart ---
  const int nb = (n1 + 1023) / 1024;
  k_scan1<<<nb, 256, 0, stream>>>(cnt, rowstart, bsums, N_, n1);
  k_scan2<<<1, 256, 0, stream>>>(bsums, nb);
  k_scan3<<<(n1 + 255) / 256, 256, 0, stream>>>(rowstart, bsums, n1);

  // --- pad slots + CSR reorder ---
  k_padfill<<<(N_ + 255) / 256, 256, 0, stream>>>(rowstart, cnt, elist, N_);
  k_fill<<<(N_ + 255) / 256, 256, 0, stream>>>((float*)cursor, 0.0f, N_);
  k_reorder<<<(E_ + 255) / 256, 256, 0, stream>>>(srcIdx, dstIdx, ew, dinv,
                                                  rowstart, cursor, elist, E_);

  // --- graph boundaries for pooling ---
  k_gbound<<<(N_ + 255) / 256, 256, 0, stream>>>(batch, gstart, N_, G_);

  const float* Wl[3]  = {w0, w1, w2};
  const float* Bl[3]  = {b0, b1, b2};
  const float* Gl[3]  = {g0, g1, g2};
  const float* BeL[3] = {be0, be1, be2};

  const float invN = 1.0f / (float)N_;

  for (int l = 0; l < 3; ++l) {
    if (l == 0) {
      k_gemm<float><<<(N_ + 127) / 128, 256, 0, stream>>>(
          x, Wl[0], Bl[0], stats, nullptr, nullptr, hhalf, N_, DIN_, 0, invN);
    } else {
      k_gemm<__half><<<(N_ + 127) / 128, 256, 0, stream>>>(
          aggh, Wl[l], Bl[l], stats, Gl[l - 1], BeL[l - 1], hhalf, N_, DH, 1, invN);
    }
    k_fill<<<1, 256, 0, stream>>>(stats, 0.0f, 2 * DH);
    k_gather<<<2048, 256, 0, stream>>>(elist, rowstart, hhalf, sc, aggh, stats, N_);
  }

  // --- fused BN2+ReLU+pooling+head ---
  k_poolhead<<<G_, 256, 0, stream>>>(aggh, stats, g2, be2, ow, gstart, ob,
                                     (float*)d_out, invN);
}

// Round 9
// 474.443 us; speedup vs baseline: 1.3326x; 1.3326x over previous
//
#include <hip/hip_runtime.h>
#include <hip/hip_fp16.h>
#include <cstdint>

#define DH 64
#define EPSV 1e-5f
#define NSHARD 8
#define GBLK 2048

__device__ __forceinline__ float atomAddF(float* p, float v) {
  return unsafeAtomicAdd(p, v);
}

__global__ void k_fill(float* __restrict__ p, float v, size_t n) {
  size_t i = blockIdx.x * (size_t)blockDim.x + threadIdx.x;
  if (i < n) p[i] = v;
}

// packed sharded histogram: one u64 atomic per edge.
// bits[40:63] = count, bits[0:39] = fixed-point (2^-24) sum of edge weights.
__global__ void k_hist(const int* __restrict__ dst, const float* __restrict__ ew,
                       unsigned long long* __restrict__ shard, int N_, int E_) {
  int e = blockIdx.x * blockDim.x + threadIdx.x;
  if (e < E_) {
    int q = dst[e];
    unsigned long long v =
        (1ull << 40) | (unsigned long long)(unsigned)(ew[e] * 16777216.0f);
    atomicAdd(&shard[(size_t)(blockIdx.x & (NSHARD - 1)) * N_ + q], v);
  }
}

// reduce shards -> cnt, dinv, sc; also zeroes cursor (deg includes +1 self-loop)
__global__ void k_redhist(const unsigned long long* __restrict__ shard,
                          int* __restrict__ cnt, float* __restrict__ dinv,
                          float* __restrict__ sc, int* __restrict__ cursor, int N_) {
  int i = blockIdx.x * blockDim.x + threadIdx.x;
  if (i < N_) {
    unsigned long long t = 0;
#pragma unroll
    for (int s = 0; s < NSHARD; ++s) t += shard[(size_t)s * N_ + i];
    float deg = 1.0f + (float)(t & 0xFFFFFFFFFFull) * (1.0f / 16777216.0f);
    cnt[i] = (int)(t >> 40);
    dinv[i] = rsqrtf(deg);
    sc[i] = 1.0f / deg;
    cursor[i] = 0;
  }
}

// ---- exclusive scan over n1 = N+1 values; value(i) = i<N ? pad8(cnt[i]) : 0 ----
__global__ __launch_bounds__(256) void k_scan1(const int* __restrict__ cnt,
                                               int* __restrict__ out,
                                               int* __restrict__ bsums,
                                               int N_, int n1) {
  __shared__ int sm[256];
  const int t = threadIdx.x;
  const int base = blockIdx.x * 1024 + t * 4;
  int v[4], lsum = 0;
#pragma unroll
  for (int j = 0; j < 4; ++j) {
    int i = base + j;
    v[j] = (i < N_) ? ((cnt[i] + 7) & ~7) : 0;   // pad rows to multiple of 8
    lsum += v[j];
  }
  sm[t] = lsum;
  __syncthreads();
  for (int o = 1; o < 256; o <<= 1) {
    int x = (t >= o) ? sm[t - o] : 0;
    __syncthreads();
    if (t >= o) sm[t] += x;
    __syncthreads();
  }
  int run = sm[t] - lsum;
#pragma unroll
  for (int j = 0; j < 4; ++j) {
    int i = base + j;
    if (i < n1) out[i] = run;
    run += v[j];
  }
  if (t == 255) bsums[blockIdx.x] = sm[255];
}

__global__ __launch_bounds__(256) void k_scan2(int* __restrict__ bsums, int nb) {
  __shared__ int sm[256];
  int t = threadIdx.x;
  int v = (t < nb) ? bsums[t] : 0;
  sm[t] = v;
  __syncthreads();
  for (int o = 1; o < 256; o <<= 1) {
    int x = (t >= o) ? sm[t - o] : 0;
    __syncthreads();
    if (t >= o) sm[t] += x;
    __syncthreads();
  }
  if (t < nb) bsums[t] = sm[t] - v;
}

__global__ void k_scan3(int* __restrict__ out, const int* __restrict__ bsums, int n1) {
  int i = blockIdx.x * blockDim.x + threadIdx.x;
  if (i < n1) out[i] += bsums[i >> 10];
}

// write 0 (src=0, norm=0) into pad slots only
__global__ void k_padfill(const int* __restrict__ rowstart, const int* __restrict__ cnt,
                          unsigned* __restrict__ elist, int N_) {
  int i = blockIdx.x * blockDim.x + threadIdx.x;
  if (i < N_) {
    int p = rowstart[i] + cnt[i], pe = rowstart[i + 1];
    for (; p < pe; ++p) elist[p] = 0u;
  }
}

// CSR reorder, fusing norm computation. elist[p] = (fp16(norm) sans sign)<<17 | src
__global__ void k_reorder(const int* __restrict__ src, const int* __restrict__ dst,
                          const float* __restrict__ ew, const float* __restrict__ dinv,
                          const int* __restrict__ rowstart, int* __restrict__ cursor,
                          unsigned* __restrict__ elist, int E_) {
  int e = blockIdx.x * blockDim.x + threadIdx.x;
  if (e < E_) {
    int s = src[e], q = dst[e];
    float nm = ew[e] * dinv[s] * dinv[q];
    unsigned h15 = (unsigned)__half_as_ushort(__float2half(nm));  // sign bit 0
    int p = rowstart[q] + atomicAdd(&cursor[q], 1);
    elist[p] = (h15 << 17) | (unsigned)s;
  }
}

// graph boundary detection on sorted batch: gstart[g] for g in [0,G]
__global__ void k_gbound(const int* __restrict__ batch, int* __restrict__ gstart,
                         int N_, int G_) {
  int i = blockIdx.x * blockDim.x + threadIdx.x;
  if (i >= N_) return;
  int b = batch[i];
  if (i == 0) {
    for (int g = 0; g <= b; ++g) gstart[g] = 0;
  }
  int nb = (i + 1 < N_) ? batch[i + 1] : G_;
  for (int g = b + 1; g <= nb; ++g) gstart[g] = i + 1;
}

// C tile 128 rows x 64 cols, 256 threads, micro-tile 4x8 per thread.
// A dtype templated (fp32 layer0 / fp16 AGG later layers).
// Optionally applies BN(prev layer)+ReLU to A while loading. Writes fp16 H.
template <typename AT>
__global__ __launch_bounds__(256) void k_gemm(
    const AT* __restrict__ A, const float* __restrict__ W,
    const float* __restrict__ bias, const float* __restrict__ stats,
    const float* __restrict__ gam, const float* __restrict__ bet,
    __half* __restrict__ Hh, int n, int K, int fuse, float invN) {
  __shared__ float As[128][17];
  __shared__ float Bs[16][64];
  __shared__ float saL[DH], sbL[DH];
  const int tid = threadIdx.x;
  const int tx = tid & 7;
  const int ty = tid >> 3;
  const int r0 = blockIdx.x * 128;
  if (fuse && tid < DH) {
    float mean = stats[tid] * invN;
    float var = stats[DH + tid] * invN - mean * mean;
    float a = rsqrtf(var + EPSV) * gam[tid];
    saL[tid] = a;
    sbL[tid] = bet[tid] - mean * a;
  }
  if (fuse) __syncthreads();
  float acc[4][8] = {};
  for (int kc = 0; kc < K; kc += 16) {
    for (int idx = tid; idx < 128 * 16; idx += 256) {
      int r = idx >> 4, c = idx & 15;
      int gr = r0 + r, gc = kc + c;
      float v = (gr < n && gc < K) ? (float)A[(size_t)gr * K + gc] : 0.0f;
      if (fuse) v = fmaxf(v * saL[gc] + sbL[gc], 0.0f);
      As[r][c] = v;
    }
    for (int idx = tid; idx < 16 * 64; idx += 256) {
      int r = idx >> 6, c = idx & 63;
      int gr = kc + r;
      Bs[r][c] = (gr < K) ? W[gr * DH + c] : 0.0f;
    }
    __syncthreads();
#pragma unroll
    for (int kk = 0; kk < 16; ++kk) {
      float a[4], b[8];
#pragma unroll
      for (int i = 0; i < 4; ++i) a[i] = As[ty * 4 + i][kk];
#pragma unroll
      for (int j = 0; j < 8; ++j) b[j] = Bs[kk][tx * 8 + j];
#pragma unroll
      for (int i = 0; i < 4; ++i)
#pragma unroll
        for (int j = 0; j < 8; ++j) acc[i][j] += a[i] * b[j];
    }
    __syncthreads();
  }
#pragma unroll
  for (int i = 0; i < 4; ++i) {
    int gr = r0 + ty * 4 + i;
    if (gr < n) {
      float h[8];
#pragma unroll
      for (int j = 0; j < 8; ++j) h[j] = acc[i][j] + bias[tx * 8 + j];
      uint4 o;
      o.x = (unsigned)__half_as_ushort(__float2half(h[0])) |
            ((unsigned)__half_as_ushort(__float2half(h[1])) << 16);
      o.y = (unsigned)__half_as_ushort(__float2half(h[2])) |
            ((unsigned)__half_as_ushort(__float2half(h[3])) << 16);
      o.z = (unsigned)__half_as_ushort(__float2half(h[4])) |
            ((unsigned)__half_as_ushort(__float2half(h[5])) << 16);
      o.w = (unsigned)__half_as_ushort(__float2half(h[6])) |
            ((unsigned)__half_as_ushort(__float2half(h[7])) << 16);
      *reinterpret_cast<uint4*>(&Hh[(size_t)gr * DH + tx * 8]) = o;
    }
  }
}

// Pull aggregation: one wave per dst row, lane d = feature d.
// Per-lane elist staging + shfl broadcast: ONE coalesced elist load per
// 64 edges, then all gather addresses come from registers -> full-row MLP.
// Stats: per-block partials (no atomics), NT streams protect L2 for H.
__global__ __launch_bounds__(256) void k_gather(
    const unsigned* __restrict__ elist, const int* __restrict__ rowstart,
    const __half* __restrict__ Hh, const float* __restrict__ sc,
    __half* __restrict__ AGGh, float* __restrict__ statp, int n) {
  const int wid = threadIdx.x >> 6;
  const int d = threadIdx.x & 63;
  const int gw = blockIdx.x * 4 + wid;
  const int nw = gridDim.x * 4;
  unsigned short* AGGu = (unsigned short*)AGGh;
  float s = 0.f, ss = 0.f;
  for (int row = gw; row < n; row += nw) {
    const int rs = rowstart[row], re = rowstart[row + 1];
    float acc = __half2float(Hh[(size_t)row * DH + d]) * sc[row];
    for (int base = rs; base < re; base += 64) {
      const int rem = re - base;                 // multiple of 8
      unsigned eL = 0u;
      if (d < rem) eL = __builtin_nontemporal_load(&elist[base + d]);
      const int m = rem < 64 ? rem : 64;         // multiple of 8
      for (int j = 0; j < m; j += 8) {
#pragma unroll
        for (int jj = 0; jj < 8; ++jj) {
          const unsigned e = __shfl(eL, j + jj, 64);
          const float v = __half2float(Hh[(size_t)(e & 0x1FFFFu) * DH + d]);
          const float nm =
              __half2float(__ushort_as_half((unsigned short)(e >> 17)));
          acc = fmaf(nm, v, acc);
        }
      }
    }
    __builtin_nontemporal_store(__half_as_ushort(__float2half(acc)),
                                &AGGu[(size_t)row * DH + d]);
    s += acc;
    ss += acc * acc;
  }
  __shared__ float sm[4][DH], sm2[4][DH];
  sm[wid][d] = s;
  sm2[wid][d] = ss;
  __syncthreads();
  if (threadIdx.x < DH) {
    float a = sm[0][d] + sm[1][d] + sm[2][d] + sm[3][d];
    float b = sm2[0][d] + sm2[1][d] + sm2[2][d] + sm2[3][d];
    __builtin_nontemporal_store(a, &statp[(size_t)blockIdx.x * 128 + d]);
    __builtin_nontemporal_store(b, &statp[(size_t)blockIdx.x * 128 + DH + d]);
  }
}

// reduce per-block stat partials: one block per stat entry (128 blocks)
__global__ __launch_bounds__(256) void k_redstats(const float* __restrict__ statp,
                                                  float* __restrict__ stats, int nblk) {
  const int t = blockIdx.x;   // 0..127
  float s = 0.f;
  for (int b = threadIdx.x; b < nblk; b += 256) s += statp[(size_t)b * 128 + t];
#pragma unroll
  for (int o = 32; o > 0; o >>= 1) s += __shfl_down(s, o, 64);
  __shared__ float sm[4];
  if ((threadIdx.x & 63) == 0) sm[threadIdx.x >> 6] = s;
  __syncthreads();
  if (threadIdx.x == 0) stats[t] = sm[0] + sm[1] + sm[2] + sm[3];
}

// fused BN+ReLU+mean-pool+head: one block per graph.
__global__ __launch_bounds__(256) void k_poolhead(
    const __half* __restrict__ AGGh, const float* __restrict__ stats,
    const float* __restrict__ gam, const float* __restrict__ bet,
    const float* __restrict__ ow, const int* __restrict__ gstart,
    const float* __restrict__ ob, float* __restrict__ out, float invN) {
  const int g = blockIdx.x;
  const int gs = gstart[g], ge = gstart[g + 1];
  const int wid = threadIdx.x >> 6;
  const int d = threadIdx.x & 63;
  float mean = stats[d] * invN;
  float var = stats[DH + d] * invN - mean * mean;
  float sa = rsqrtf(var + EPSV) * gam[d];
  float sb = bet[d] - mean * sa;
  const float w = ow[d];
  float acc = 0.f;
  for (int row = gs + wid; row < ge; row += 4)
    acc += fmaxf(__half2float(AGGh[(size_t)row * DH + d]) * sa + sb, 0.f) * w;
#pragma unroll
  for (int off = 32; off > 0; off >>= 1) acc += __shfl_down(acc, off, 64);
  __shared__ float sm[4];
  if (d == 0) sm[wid] = acc;
  __syncthreads();
  if (threadIdx.x == 0) {
    float s = sm[0] + sm[1] + sm[2] + sm[3];
    float cnt = (float)(ge - gs);
    out[g] = s / fmaxf(cnt, 1.0f) + ob[0];
  }
}

extern "C" void kernel_launch(void* const* d_in, const int* in_sizes, int n_in,
                              void* d_out, int out_size, void* d_ws, size_t ws_size,
                              hipStream_t stream) {
  const float* x    = (const float*)d_in[0];
  const int*   ei   = (const int*)d_in[1];
  const float* ew   = (const float*)d_in[2];
  const int*   batch= (const int*)d_in[3];
  const float* w0   = (const float*)d_in[4];
  const float* b0   = (const float*)d_in[5];
  const float* g0   = (const float*)d_in[6];
  const float* be0  = (const float*)d_in[7];
  const float* w1   = (const float*)d_in[8];
  const float* b1   = (const float*)d_in[9];
  const float* g1   = (const float*)d_in[10];
  const float* be1  = (const float*)d_in[11];
  const float* w2   = (const float*)d_in[12];
  const float* b2   = (const float*)d_in[13];
  const float* g2   = (const float*)d_in[14];
  const float* be2  = (const float*)d_in[15];
  const float* ow   = (const float*)d_in[16];
  const float* ob   = (const float*)d_in[17];

  const int N_  = in_sizes[3];
  const int E_  = in_sizes[2];
  const int DIN_= in_sizes[0] / N_;
  const int G_  = out_size;
  const int* srcIdx = ei;
  const int* dstIdx = ei + E_;
  const int n1 = N_ + 1;
  const size_t epad = (size_t)E_ + 7ull * N_;   // max padded edge slots

  float* ws = (float*)d_ws;
  size_t off = 0;
  unsigned* elist = (unsigned*)(ws + off); off += epad;
  unsigned long long* shard = (unsigned long long*)(ws + off); off += (size_t)2 * NSHARD * N_;
  float* dinv     = ws + off; off += N_;
  float* sc       = ws + off; off += N_;
  int*   cnt      = (int*)(ws + off); off += N_;
  int*   cursor   = (int*)(ws + off); off += N_;
  int*   rowstart = (int*)(ws + off); off += n1 + 1;
  int*   bsums    = (int*)(ws + off); off += 256;
  int*   gstart   = (int*)(ws + off); off += G_ + 1;
  __half* hhalf   = (__half*)(ws + off); off += (size_t)N_ * DH / 2;
  __half* aggh    = (__half*)(ws + off); off += (size_t)N_ * DH / 2;
  float* stats    = ws + off; off += 2 * DH;
  float* statp    = ws + off; off += (size_t)GBLK * 128;
  (void)ws_size; (void)n_in;

  // --- packed sharded histogram ---
  k_fill<<<(int)(((size_t)2 * NSHARD * N_ + 255) / 256), 256, 0, stream>>>(
      (float*)shard, 0.0f, (size_t)2 * NSHARD * N_);
  k_hist<<<(E_ + 255) / 256, 256, 0, stream>>>(dstIdx, ew, shard, N_, E_);
  k_redhist<<<(N_ + 255) / 256, 256, 0, stream>>>(shard, cnt, dinv, sc, cursor, N_);

  // --- exclusive scan padded cnt -> rowstart ---
  const int nb = (n1 + 1023) / 1024;
  k_scan1<<<nb, 256, 0, stream>>>(cnt, rowstart, bsums, N_, n1);
  k_scan2<<<1, 256, 0, stream>>>(bsums, nb);
  k_scan3<<<(n1 + 255) / 256, 256, 0, stream>>>(rowstart, bsums, n1);

  // --- pad slots + CSR reorder ---
  k_padfill<<<(N_ + 255) / 256, 256, 0, stream>>>(rowstart, cnt, elist, N_);
  k_reorder<<<(E_ + 255) / 256, 256, 0, stream>>>(srcIdx, dstIdx, ew, dinv,
                                                  rowstart, cursor, elist, E_);

  // --- graph boundaries for pooling ---
  k_gbound<<<(N_ + 255) / 256, 256, 0, stream>>>(batch, gstart, N_, G_);

  const float* Wl[3]  = {w0, w1, w2};
  const float* Bl[3]  = {b0, b1, b2};
  const float* Gl[3]  = {g0, g1, g2};
  const float* BeL[3] = {be0, be1, be2};

  const float invN = 1.0f / (float)N_;

  for (int l = 0; l < 3; ++l) {
    if (l == 0) {
      k_gemm<float><<<(N_ + 127) / 128, 256, 0, stream>>>(
          x, Wl[0], Bl[0], stats, nullptr, nullptr, hhalf, N_, DIN_, 0, invN);
    } else {
      k_gemm<__half><<<(N_ + 127) / 128, 256, 0, stream>>>(
          aggh, Wl[l], Bl[l], stats, Gl[l - 1], BeL[l - 1], hhalf, N_, DH, 1, invN);
    }
    k_gather<<<GBLK, 256, 0, stream>>>(elist, rowstart, hhalf, sc, aggh, statp, N_);
    k_redstats<<<128, 256, 0, stream>>>(statp, stats, GBLK);
  }

  // --- fused BN2+ReLU+pooling+head ---
  k_poolhead<<<G_, 256, 0, stream>>>(aggh, stats, g2, be2, ow, gstart, ob,
                                     (float*)d_out, invN);
}

// Round 10
// 461.747 us; speedup vs baseline: 1.3692x; 1.0275x over previous
//
#include <hip/hip_runtime.h>
#include <hip/hip_fp16.h>
#include <cstdint>

#define DH 64
#define EPSV 1e-5f
#define NSHARD 8
#define GBLK 2048
#define NBUK 256
#define BROWS 512
#define BINJ 8

__device__ __forceinline__ float atomAddF(float* p, float v) {
  return unsafeAtomicAdd(p, v);
}

__global__ void k_fill(float* __restrict__ p, float v, size_t n) {
  size_t i = blockIdx.x * (size_t)blockDim.x + threadIdx.x;
  if (i < n) p[i] = v;
}

// packed sharded histogram: one u64 atomic per edge.
// bits[40:63] = count, bits[0:39] = fixed-point (2^-24) sum of edge weights.
__global__ void k_hist(const int* __restrict__ dst, const float* __restrict__ ew,
                       unsigned long long* __restrict__ shard, int N_, int E_) {
  int e = blockIdx.x * blockDim.x + threadIdx.x;
  if (e < E_) {
    int q = dst[e];
    unsigned long long v =
        (1ull << 40) | (unsigned long long)(unsigned)(ew[e] * 16777216.0f);
    atomicAdd(&shard[(size_t)(blockIdx.x & (NSHARD - 1)) * N_ + q], v);
  }
}

// reduce shards -> cnt, dinv, sc  (deg includes +1 self-loop)
__global__ void k_redhist(const unsigned long long* __restrict__ shard,
                          int* __restrict__ cnt, float* __restrict__ dinv,
                          float* __restrict__ sc, int N_) {
  int i = blockIdx.x * blockDim.x + threadIdx.x;
  if (i < N_) {
    unsigned long long t = 0;
#pragma unroll
    for (int s = 0; s < NSHARD; ++s) t += shard[(size_t)s * N_ + i];
    float deg = 1.0f + (float)(t & 0xFFFFFFFFFFull) * (1.0f / 16777216.0f);
    cnt[i] = (int)(t >> 40);
    dinv[i] = rsqrtf(deg);
    sc[i] = 1.0f / deg;
  }
}

// ---- exclusive scan over n1 = N+1 values; value(i) = i<N ? pad8(cnt[i]) : 0 ----
__global__ __launch_bounds__(256) void k_scan1(const int* __restrict__ cnt,
                                               int* __restrict__ out,
                                               int* __restrict__ bsums,
                                               int N_, int n1) {
  __shared__ int sm[256];
  const int t = threadIdx.x;
  const int base = blockIdx.x * 1024 + t * 4;
  int v[4], lsum = 0;
#pragma unroll
  for (int j = 0; j < 4; ++j) {
    int i = base + j;
    v[j] = (i < N_) ? ((cnt[i] + 7) & ~7) : 0;   // pad rows to multiple of 8
    lsum += v[j];
  }
  sm[t] = lsum;
  __syncthreads();
  for (int o = 1; o < 256; o <<= 1) {
    int x = (t >= o) ? sm[t - o] : 0;
    __syncthreads();
    if (t >= o) sm[t] += x;
    __syncthreads();
  }
  int run = sm[t] - lsum;
#pragma unroll
  for (int j = 0; j < 4; ++j) {
    int i = base + j;
    if (i < n1) out[i] = run;
    run += v[j];
  }
  if (t == 255) bsums[blockIdx.x] = sm[255];
}

__global__ __launch_bounds__(256) void k_scan2(int* __restrict__ bsums, int nb) {
  __shared__ int sm[256];
  int t = threadIdx.x;
  int v = (t < nb) ? bsums[t] : 0;
  sm[t] = v;
  __syncthreads();
  for (int o = 1; o < 256; o <<= 1) {
    int x = (t >= o) ? sm[t - o] : 0;
    __syncthreads();
    if (t >= o) sm[t] += x;
    __syncthreads();
  }
  if (t < nb) bsums[t] = sm[t] - v;
}

__global__ void k_scan3(int* __restrict__ out, const int* __restrict__ bsums, int n1) {
  int i = blockIdx.x * blockDim.x + threadIdx.x;
  if (i < n1) out[i] += bsums[i >> 10];
}

// gcur[b] = padded base of bucket b (1 block, 256 threads)
__global__ void k_gcur(const int* __restrict__ rowstart, unsigned* __restrict__ gcur,
                       int N_) {
  int t = threadIdx.x;
  int r = t * BROWS;
  if (r > N_) r = N_;
  gcur[t] = (unsigned)rowstart[r];
}

// write 0 (src=0, norm=0) into pad slots only
__global__ void k_padfill(const int* __restrict__ rowstart, const int* __restrict__ cnt,
                          unsigned* __restrict__ elist, int N_) {
  int i = blockIdx.x * blockDim.x + threadIdx.x;
  if (i < N_) {
    int p = rowstart[i] + cnt[i], pe = rowstart[i + 1];
    for (; p < pe; ++p) elist[p] = 0u;
  }
}

// Pass 1: bin edges by dst bucket. Per-block LDS counting -> one global
// atomic per (block,bucket) -> contiguous per-bucket runs of 8B payloads.
__global__ __launch_bounds__(256) void k_bin(
    const int* __restrict__ src, const int* __restrict__ dst,
    const float* __restrict__ ew, const float* __restrict__ dinv,
    unsigned* __restrict__ gcur, unsigned long long* __restrict__ bstage, int E_) {
  __shared__ unsigned cntL[NBUK], offL[NBUK], runL[NBUK];
  const int t = threadIdx.x;
  const int base = blockIdx.x * (256 * BINJ);
  cntL[t] = 0;
  runL[t] = 0;
  __syncthreads();
  unsigned lo[BINJ];
  int dd[BINJ];
#pragma unroll
  for (int j = 0; j < BINJ; ++j) {
    int e = base + j * 256 + t;
    dd[j] = -1;
    if (e < E_) {
      int s = src[e], q = dst[e];
      float nm = ew[e] * dinv[s] * dinv[q];
      unsigned h15 = (unsigned)__half_as_ushort(__float2half(nm));
      lo[j] = (h15 << 17) | (unsigned)s;
      dd[j] = q;
      atomicAdd(&cntL[q >> 9], 1u);
    }
  }
  __syncthreads();
  offL[t] = cntL[t] ? atomicAdd(&gcur[t], cntL[t]) : 0u;
  __syncthreads();
#pragma unroll
  for (int j = 0; j < BINJ; ++j) {
    if (dd[j] >= 0) {
      int b = dd[j] >> 9;
      unsigned p = offL[b] + atomicAdd(&runL[b], 1u);
      bstage[p] = ((unsigned long long)(unsigned)dd[j] << 32) | lo[j];
    }
  }
}

// Pass 2: one block per bucket; LDS row cursors place payloads into final
// CSR slots. All writes land in the bucket's ~36KB elist window (L2-local).
__global__ __launch_bounds__(256) void k_fin(
    const unsigned long long* __restrict__ bstage, const int* __restrict__ rowstart,
    const unsigned* __restrict__ gcur, unsigned* __restrict__ elist, int N_) {
  __shared__ unsigned lcur[BROWS];
  __shared__ int rsL[BROWS + 1];
  const int b = blockIdx.x;
  const int r0 = b * BROWS;
  const int t = threadIdx.x;
  for (int i = t; i < BROWS; i += 256) lcur[i] = 0;
  for (int i = t; i <= BROWS; i += 256) {
    int r = r0 + i;
    if (r > N_) r = N_;
    rsL[i] = rowstart[r];
  }
  __syncthreads();
  const unsigned beg = (unsigned)rsL[0];
  const unsigned end = gcur[b];
  for (unsigned p = beg + t; p < end; p += 256) {
    unsigned long long v = bstage[p];
    int r = (int)(v >> 32) - r0;
    unsigned slot = (unsigned)rsL[r] + atomicAdd(&lcur[r], 1u);
    elist[slot] = (unsigned)v;
  }
}

// graph boundary detection on sorted batch: gstart[g] for g in [0,G]
__global__ void k_gbound(const int* __restrict__ batch, int* __restrict__ gstart,
                         int N_, int G_) {
  int i = blockIdx.x * blockDim.x + threadIdx.x;
  if (i >= N_) return;
  int b = batch[i];
  if (i == 0) {
    for (int g = 0; g <= b; ++g) gstart[g] = 0;
  }
  int nb = (i + 1 < N_) ? batch[i + 1] : G_;
  for (int g = b + 1; g <= nb; ++g) gstart[g] = i + 1;
}

// C tile 128 rows x 64 cols, 256 threads, micro-tile 4x8 per thread.
template <typename AT>
__global__ __launch_bounds__(256) void k_gemm(
    const AT* __restrict__ A, const float* __restrict__ W,
    const float* __restrict__ bias, const float* __restrict__ stats,
    const float* __restrict__ gam, const float* __restrict__ bet,
    __half* __restrict__ Hh, int n, int K, int fuse, float invN) {
  __shared__ float As[128][17];
  __shared__ float Bs[16][64];
  __shared__ float saL[DH], sbL[DH];
  const int tid = threadIdx.x;
  const int tx = tid & 7;
  const int ty = tid >> 3;
  const int r0 = blockIdx.x * 128;
  if (fuse && tid < DH) {
    float mean = stats[tid] * invN;
    float var = stats[DH + tid] * invN - mean * mean;
    float a = rsqrtf(var + EPSV) * gam[tid];
    saL[tid] = a;
    sbL[tid] = bet[tid] - mean * a;
  }
  if (fuse) __syncthreads();
  float acc[4][8] = {};
  for (int kc = 0; kc < K; kc += 16) {
    for (int idx = tid; idx < 128 * 16; idx += 256) {
      int r = idx >> 4, c = idx & 15;
      int gr = r0 + r, gc = kc + c;
      float v = (gr < n && gc < K) ? (float)A[(size_t)gr * K + gc] : 0.0f;
      if (fuse) v = fmaxf(v * saL[gc] + sbL[gc], 0.0f);
      As[r][c] = v;
    }
    for (int idx = tid; idx < 16 * 64; idx += 256) {
      int r = idx >> 6, c = idx & 63;
      int gr = kc + r;
      Bs[r][c] = (gr < K) ? W[gr * DH + c] : 0.0f;
    }
    __syncthreads();
#pragma unroll
    for (int kk = 0; kk < 16; ++kk) {
      float a[4], b[8];
#pragma unroll
      for (int i = 0; i < 4; ++i) a[i] = As[ty * 4 + i][kk];
#pragma unroll
      for (int j = 0; j < 8; ++j) b[j] = Bs[kk][tx * 8 + j];
#pragma unroll
      for (int i = 0; i < 4; ++i)
#pragma unroll
        for (int j = 0; j < 8; ++j) acc[i][j] += a[i] * b[j];
    }
    __syncthreads();
  }
#pragma unroll
  for (int i = 0; i < 4; ++i) {
    int gr = r0 + ty * 4 + i;
    if (gr < n) {
      float h[8];
#pragma unroll
      for (int j = 0; j < 8; ++j) h[j] = acc[i][j] + bias[tx * 8 + j];
      uint4 o;
      o.x = (unsigned)__half_as_ushort(__float2half(h[0])) |
            ((unsigned)__half_as_ushort(__float2half(h[1])) << 16);
      o.y = (unsigned)__half_as_ushort(__float2half(h[2])) |
            ((unsigned)__half_as_ushort(__float2half(h[3])) << 16);
      o.z = (unsigned)__half_as_ushort(__float2half(h[4])) |
            ((unsigned)__half_as_ushort(__float2half(h[5])) << 16);
      o.w = (unsigned)__half_as_ushort(__float2half(h[6])) |
            ((unsigned)__half_as_ushort(__float2half(h[7])) << 16);
      *reinterpret_cast<uint4*>(&Hh[(size_t)gr * DH + tx * 8]) = o;
    }
  }
}

// Pull aggregation: one wave per dst row, lane d = feature d.
// Per-lane elist staging + shfl broadcast; per-block stats partials.
__global__ __launch_bounds__(256) void k_gather(
    const unsigned* __restrict__ elist, const int* __restrict__ rowstart,
    const __half* __restrict__ Hh, const float* __restrict__ sc,
    __half* __restrict__ AGGh, float* __restrict__ statp, int n) {
  const int wid = threadIdx.x >> 6;
  const int d = threadIdx.x & 63;
  const int gw = blockIdx.x * 4 + wid;
  const int nw = gridDim.x * 4;
  unsigned short* AGGu = (unsigned short*)AGGh;
  float s = 0.f, ss = 0.f;
  for (int row = gw; row < n; row += nw) {
    const int rs = rowstart[row], re = rowstart[row + 1];
    float acc = __half2float(Hh[(size_t)row * DH + d]) * sc[row];
    for (int base = rs; base < re; base += 64) {
      const int rem = re - base;                 // multiple of 8
      unsigned eL = 0u;
      if (d < rem) eL = __builtin_nontemporal_load(&elist[base + d]);
      const int m = rem < 64 ? rem : 64;         // multiple of 8
      for (int j = 0; j < m; j += 8) {
#pragma unroll
        for (int jj = 0; jj < 8; ++jj) {
          const unsigned e = __shfl(eL, j + jj, 64);
          const float v = __half2float(Hh[(size_t)(e & 0x1FFFFu) * DH + d]);
          const float nm =
              __half2float(__ushort_as_half((unsigned short)(e >> 17)));
          acc = fmaf(nm, v, acc);
        }
      }
    }
    __builtin_nontemporal_store(__half_as_ushort(__float2half(acc)),
                                &AGGu[(size_t)row * DH + d]);
    s += acc;
    ss += acc * acc;
  }
  __shared__ float sm[4][DH], sm2[4][DH];
  sm[wid][d] = s;
  sm2[wid][d] = ss;
  __syncthreads();
  if (threadIdx.x < DH) {
    float a = sm[0][d] + sm[1][d] + sm[2][d] + sm[3][d];
    float b = sm2[0][d] + sm2[1][d] + sm2[2][d] + sm2[3][d];
    __builtin_nontemporal_store(a, &statp[(size_t)blockIdx.x * 128 + d]);
    __builtin_nontemporal_store(b, &statp[(size_t)blockIdx.x * 128 + DH + d]);
  }
}

// reduce per-block stat partials: one block per stat entry (128 blocks)
__global__ __launch_bounds__(256) void k_redstats(const float* __restrict__ statp,
                                                  float* __restrict__ stats, int nblk) {
  const int t = blockIdx.x;   // 0..127
  float s = 0.f;
  for (int b = threadIdx.x; b < nblk; b += 256) s += statp[(size_t)b * 128 + t];
#pragma unroll
  for (int o = 32; o > 0; o >>= 1) s += __shfl_down(s, o, 64);
  __shared__ float sm[4];
  if ((threadIdx.x & 63) == 0) sm[threadIdx.x >> 6] = s;
  __syncthreads();
  if (threadIdx.x == 0) stats[t] = sm[0] + sm[1] + sm[2] + sm[3];
}

// fused BN+ReLU+mean-pool+head: one block per graph.
__global__ __launch_bounds__(256) void k_poolhead(
    const __half* __restrict__ AGGh, const float* __restrict__ stats,
    const float* __restrict__ gam, const float* __restrict__ bet,
    const float* __restrict__ ow, const int* __restrict__ gstart,
    const float* __restrict__ ob, float* __restrict__ out, float invN) {
  const int g = blockIdx.x;
  const int gs = gstart[g], ge = gstart[g + 1];
  const int wid = threadIdx.x >> 6;
  const int d = threadIdx.x & 63;
  float mean = stats[d] * invN;
  float var = stats[DH + d] * invN - mean * mean;
  float sa = rsqrtf(var + EPSV) * gam[d];
  float sb = bet[d] - mean * sa;
  const float w = ow[d];
  float acc = 0.f;
  for (int row = gs + wid; row < ge; row += 4)
    acc += fmaxf(__half2float(AGGh[(size_t)row * DH + d]) * sa + sb, 0.f) * w;
#pragma unroll
  for (int off = 32; off > 0; off >>= 1) acc += __shfl_down(acc, off, 64);
  __shared__ float sm[4];
  if (d == 0) sm[wid] = acc;
  __syncthreads();
  if (threadIdx.x == 0) {
    float s = sm[0] + sm[1] + sm[2] + sm[3];
    float cnt = (float)(ge - gs);
    out[g] = s / fmaxf(cnt, 1.0f) + ob[0];
  }
}

extern "C" void kernel_launch(void* const* d_in, const int* in_sizes, int n_in,
                              void* d_out, int out_size, void* d_ws, size_t ws_size,
                              hipStream_t stream) {
  const float* x    = (const float*)d_in[0];
  const int*   ei   = (const int*)d_in[1];
  const float* ew   = (const float*)d_in[2];
  const int*   batch= (const int*)d_in[3];
  const float* w0   = (const float*)d_in[4];
  const float* b0   = (const float*)d_in[5];
  const float* g0   = (const float*)d_in[6];
  const float* be0  = (const float*)d_in[7];
  const float* w1   = (const float*)d_in[8];
  const float* b1   = (const float*)d_in[9];
  const float* g1   = (const float*)d_in[10];
  const float* be1  = (const float*)d_in[11];
  const float* w2   = (const float*)d_in[12];
  const float* b2   = (const float*)d_in[13];
  const float* g2   = (const float*)d_in[14];
  const float* be2  = (const float*)d_in[15];
  const float* ow   = (const float*)d_in[16];
  const float* ob   = (const float*)d_in[17];

  const int N_  = in_sizes[3];
  const int E_  = in_sizes[2];
  const int DIN_= in_sizes[0] / N_;
  const int G_  = out_size;
  const int* srcIdx = ei;
  const int* dstIdx = ei + E_;
  const int n1 = N_ + 1;
  const size_t epad = (size_t)E_ + 7ull * N_;   // max padded edge slots

  float* ws = (float*)d_ws;
  size_t off = 0;
  // bstage (pass-1 staging) aliases shard: shard is dead before k_bin runs.
  unsigned long long* bstage = (unsigned long long*)(ws + off);
  unsigned long long* shard  = bstage;
  off += 2 * epad;                                   // epad u64
  unsigned* elist = (unsigned*)(ws + off); off += epad;
  float* dinv     = ws + off; off += N_;
  float* sc       = ws + off; off += N_;
  int*   cnt      = (int*)(ws + off); off += N_;
  int*   rowstart = (int*)(ws + off); off += n1 + 1;
  int*   bsums    = (int*)(ws + off); off += 256;
  unsigned* gcur  = (unsigned*)(ws + off); off += NBUK;
  int*   gstart   = (int*)(ws + off); off += G_ + 1;
  __half* hhalf   = (__half*)(ws + off); off += (size_t)N_ * DH / 2;
  __half* aggh    = (__half*)(ws + off); off += (size_t)N_ * DH / 2;
  float* stats    = ws + off; off += 2 * DH;
  float* statp    = ws + off; off += (size_t)GBLK * 128;
  (void)ws_size; (void)n_in;

  // --- packed sharded histogram ---
  k_fill<<<(int)(((size_t)2 * NSHARD * N_ + 255) / 256), 256, 0, stream>>>(
      (float*)shard, 0.0f, (size_t)2 * NSHARD * N_);
  k_hist<<<(E_ + 255) / 256, 256, 0, stream>>>(dstIdx, ew, shard, N_, E_);
  k_redhist<<<(N_ + 255) / 256, 256, 0, stream>>>(shard, cnt, dinv, sc, N_);

  // --- exclusive scan padded cnt -> rowstart ---
  const int nb = (n1 + 1023) / 1024;
  k_scan1<<<nb, 256, 0, stream>>>(cnt, rowstart, bsums, N_, n1);
  k_scan2<<<1, 256, 0, stream>>>(bsums, nb);
  k_scan3<<<(n1 + 255) / 256, 256, 0, stream>>>(rowstart, bsums, n1);

  // --- two-pass binned CSR build ---
  k_gcur<<<1, 256, 0, stream>>>(rowstart, gcur, N_);
  k_padfill<<<(N_ + 255) / 256, 256, 0, stream>>>(rowstart, cnt, elist, N_);
  k_bin<<<(E_ + 256 * BINJ - 1) / (256 * BINJ), 256, 0, stream>>>(
      srcIdx, dstIdx, ew, dinv, gcur, bstage, E_);
  k_fin<<<NBUK, 256, 0, stream>>>(bstage, rowstart, gcur, elist, N_);

  // --- graph boundaries for pooling ---
  k_gbound<<<(N_ + 255) / 256, 256, 0, stream>>>(batch, gstart, N_, G_);

  const float* Wl[3]  = {w0, w1, w2};
  const float* Bl[3]  = {b0, b1, b2};
  const float* Gl[3]  = {g0, g1, g2};
  const float* BeL[3] = {be0, be1, be2};

  const float invN = 1.0f / (float)N_;

  for (int l = 0; l < 3; ++l) {
    if (l == 0) {
      k_gemm<float><<<(N_ + 127) / 128, 256, 0, stream>>>(
          x, Wl[0], Bl[0], stats, nullptr, nullptr, hhalf, N_, DIN_, 0, invN);
    } else {
      k_gemm<__half><<<(N_ + 127) / 128, 256, 0, stream>>>(
          aggh, Wl[l], Bl[l], stats, Gl[l - 1], BeL[l - 1], hhalf, N_, DH, 1, invN);
    }
    k_gather<<<GBLK, 256, 0, stream>>>(elist, rowstart, hhalf, sc, aggh, statp, N_);
    k_redstats<<<128, 256, 0, stream>>>(statp, stats, GBLK);
  }

  // --- fused BN2+ReLU+pooling+head ---
  k_poolhead<<<G_, 256, 0, stream>>>(aggh, stats, g2, be2, ow, gstart, ob,
                                     (float*)d_out, invN);
}

// Round 11
// 385.022 us; speedup vs baseline: 1.6421x; 1.1993x over previous
//
#include <hip/hip_runtime.h>
#include <hip/hip_fp16.h>
#include <cstdint>

#define DH 64
#define EPSV 1e-5f
#define GBLK 2048
#define NBUK 256
#define BROWS 512
#define BINJ 8
#define CAP 12288

__global__ void k_fill(float* __restrict__ p, float v, size_t n) {
  size_t i = blockIdx.x * (size_t)blockDim.x + threadIdx.x;
  if (i < n) p[i] = v;
}

// init bucket stage cursors: gcur0[b] = b*CAP
__global__ void k_gcur0(unsigned* __restrict__ gcur0) {
  gcur0[threadIdx.x] = (unsigned)(threadIdx.x * CAP);
}

// Pass 1: bin edges by dst bucket (no dinv dependency).
// payload u64: hi = (dst&511)<<17 | src, lo = fp32 ew bits.
__global__ __launch_bounds__(256) void k_bin0(
    const int* __restrict__ src, const int* __restrict__ dst,
    const float* __restrict__ ew, unsigned* __restrict__ gcur0,
    unsigned long long* __restrict__ bstage, int E_) {
  __shared__ unsigned cntL[NBUK], offL[NBUK], runL[NBUK];
  const int t = threadIdx.x;
  const int base = blockIdx.x * (256 * BINJ);
  cntL[t] = 0;
  runL[t] = 0;
  __syncthreads();
  unsigned hi[BINJ], lo[BINJ];
  int bb[BINJ];
#pragma unroll
  for (int j = 0; j < BINJ; ++j) {
    int e = base + j * 256 + t;
    bb[j] = -1;
    if (e < E_) {
      int q = dst[e];
      hi[j] = ((unsigned)(q & (BROWS - 1)) << 17) | (unsigned)src[e];
      lo[j] = __float_as_uint(ew[e]);
      bb[j] = q >> 9;
      atomicAdd(&cntL[bb[j]], 1u);
    }
  }
  __syncthreads();
  offL[t] = cntL[t] ? atomicAdd(&gcur0[t], cntL[t]) : 0u;
  __syncthreads();
#pragma unroll
  for (int j = 0; j < BINJ; ++j) {
    if (bb[j] >= 0) {
      unsigned p = offL[bb[j]] + atomicAdd(&runL[bb[j]], 1u);
      bstage[p] = ((unsigned long long)hi[j] << 32) | lo[j];
    }
  }
}

// Per-bucket histogram from staged runs: cnt, dinv, sc (deterministic:
// integer LDS atomics, fixed-point 2^-24 ew sum; deg includes +1 self-loop).
__global__ __launch_bounds__(256) void k_bcnt(
    const unsigned long long* __restrict__ bstage, const unsigned* __restrict__ gcur0,
    int* __restrict__ cnt, float* __restrict__ dinv, float* __restrict__ sc, int N_) {
  __shared__ unsigned cntL[BROWS], degL[BROWS];
  const int b = blockIdx.x, t = threadIdx.x;
  for (int i = t; i < BROWS; i += 256) {
    cntL[i] = 0;
    degL[i] = 0;
  }
  __syncthreads();
  const unsigned beg = (unsigned)(b * CAP), end = gcur0[b];
  for (unsigned p = beg + t; p < end; p += 256) {
    unsigned long long v = bstage[p];
    unsigned r = (unsigned)(v >> 49);                 // dst_local
    float w = __uint_as_float((unsigned)v);
    atomicAdd(&cntL[r], 1u);
    atomicAdd(&degL[r], (unsigned)(w * 16777216.0f));
  }
  __syncthreads();
  for (int i = t; i < BROWS; i += 256) {
    int r = b * BROWS + i;
    if (r < N_) {
      float deg = 1.0f + (float)degL[i] * (1.0f / 16777216.0f);
      cnt[r] = (int)cntL[i];
      dinv[r] = rsqrtf(deg);
      sc[r] = 1.0f / deg;
    }
  }
}

// ---- exclusive scan over n1 = N+1 values; value(i) = i<N ? pad8(cnt[i]) : 0 ----
__global__ __launch_bounds__(256) void k_scan1(const int* __restrict__ cnt,
                                               int* __restrict__ out,
                                               int* __restrict__ bsums,
                                               int N_, int n1) {
  __shared__ int sm[256];
  const int t = threadIdx.x;
  const int base = blockIdx.x * 1024 + t * 4;
  int v[4], lsum = 0;
#pragma unroll
  for (int j = 0; j < 4; ++j) {
    int i = base + j;
    v[j] = (i < N_) ? ((cnt[i] + 7) & ~7) : 0;   // pad rows to multiple of 8
    lsum += v[j];
  }
  sm[t] = lsum;
  __syncthreads();
  for (int o = 1; o < 256; o <<= 1) {
    int x = (t >= o) ? sm[t - o] : 0;
    __syncthreads();
    if (t >= o) sm[t] += x;
    __syncthreads();
  }
  int run = sm[t] - lsum;
#pragma unroll
  for (int j = 0; j < 4; ++j) {
    int i = base + j;
    if (i < n1) out[i] = run;
    run += v[j];
  }
  if (t == 255) bsums[blockIdx.x] = sm[255];
}

__global__ __launch_bounds__(256) void k_scan2(int* __restrict__ bsums, int nb) {
  __shared__ int sm[256];
  int t = threadIdx.x;
  int v = (t < nb) ? bsums[t] : 0;
  sm[t] = v;
  __syncthreads();
  for (int o = 1; o < 256; o <<= 1) {
    int x = (t >= o) ? sm[t - o] : 0;
    __syncthreads();
    if (t >= o) sm[t] += x;
    __syncthreads();
  }
  if (t < nb) bsums[t] = sm[t] - v;
}

__global__ void k_scan3(int* __restrict__ out, const int* __restrict__ bsums, int n1) {
  int i = blockIdx.x * blockDim.x + threadIdx.x;
  if (i < n1) out[i] += bsums[i >> 10];
}

// Pass 2: one block per bucket; compute norm + place into CSR slots via LDS
// cursors; fill pad slots from the same cursors (all writes L2-window-local).
__global__ __launch_bounds__(256) void k_fin(
    const unsigned long long* __restrict__ bstage, const int* __restrict__ rowstart,
    const unsigned* __restrict__ gcur0, const float* __restrict__ dinv,
    unsigned* __restrict__ elist, int N_) {
  __shared__ unsigned lcur[BROWS];
  __shared__ int rsL[BROWS + 1];
  __shared__ float dvL[BROWS];
  const int b = blockIdx.x, t = threadIdx.x;
  const int r0 = b * BROWS;
  for (int i = t; i < BROWS; i += 256) {
    lcur[i] = 0;
    int r = r0 + i;
    dvL[i] = (r < N_) ? dinv[r] : 0.f;
  }
  for (int i = t; i <= BROWS; i += 256) {
    int r = r0 + i;
    if (r > N_) r = N_;
    rsL[i] = rowstart[r];
  }
  __syncthreads();
  const unsigned beg = (unsigned)(b * CAP), end = gcur0[b];
  for (unsigned p = beg + t; p < end; p += 256) {
    unsigned long long v = bstage[p];
    unsigned hi = (unsigned)(v >> 32);
    unsigned r = hi >> 17;
    unsigned s = hi & 0x1FFFFu;
    float w = __uint_as_float((unsigned)v);
    float nm = w * dinv[s] * dvL[r];
    unsigned h15 = (unsigned)__half_as_ushort(__float2half(nm));
    unsigned slot = (unsigned)rsL[r] + atomicAdd(&lcur[r], 1u);
    elist[slot] = (h15 << 17) | s;
  }
  __syncthreads();
  for (int i = t; i < BROWS; i += 256) {
    unsigned p = (unsigned)rsL[i] + lcur[i];
    const unsigned pe = (unsigned)rsL[i + 1];
    for (; p < pe; ++p) elist[p] = 0u;
  }
}

// graph boundary detection on sorted batch: gstart[g] for g in [0,G]
__global__ void k_gbound(const int* __restrict__ batch, int* __restrict__ gstart,
                         int N_, int G_) {
  int i = blockIdx.x * blockDim.x + threadIdx.x;
  if (i >= N_) return;
  int b = batch[i];
  if (i == 0) {
    for (int g = 0; g <= b; ++g) gstart[g] = 0;
  }
  int nb = (i + 1 < N_) ? batch[i + 1] : G_;
  for (int g = b + 1; g <= nb; ++g) gstart[g] = i + 1;
}

// C tile 128 rows x 64 cols, 256 threads, micro-tile 4x8 per thread.
template <typename AT>
__global__ __launch_bounds__(256) void k_gemm(
    const AT* __restrict__ A, const float* __restrict__ W,
    const float* __restrict__ bias, const float* __restrict__ stats,
    const float* __restrict__ gam, const float* __restrict__ bet,
    __half* __restrict__ Hh, int n, int K, int fuse, float invN) {
  __shared__ float As[128][17];
  __shared__ float Bs[16][64];
  __shared__ float saL[DH], sbL[DH];
  const int tid = threadIdx.x;
  const int tx = tid & 7;
  const int ty = tid >> 3;
  const int r0 = blockIdx.x * 128;
  if (fuse && tid < DH) {
    float mean = stats[tid] * invN;
    float var = stats[DH + tid] * invN - mean * mean;
    float a = rsqrtf(var + EPSV) * gam[tid];
    saL[tid] = a;
    sbL[tid] = bet[tid] - mean * a;
  }
  if (fuse) __syncthreads();
  float acc[4][8] = {};
  for (int kc = 0; kc < K; kc += 16) {
    for (int idx = tid; idx < 128 * 16; idx += 256) {
      int r = idx >> 4, c = idx & 15;
      int gr = r0 + r, gc = kc + c;
      float v = (gr < n && gc < K) ? (float)A[(size_t)gr * K + gc] : 0.0f;
      if (fuse) v = fmaxf(v * saL[gc] + sbL[gc], 0.0f);
      As[r][c] = v;
    }
    for (int idx = tid; idx < 16 * 64; idx += 256) {
      int r = idx >> 6, c = idx & 63;
      int gr = kc + r;
      Bs[r][c] = (gr < K) ? W[gr * DH + c] : 0.0f;
    }
    __syncthreads();
#pragma unroll
    for (int kk = 0; kk < 16; ++kk) {
      float a[4], b[8];
#pragma unroll
      for (int i = 0; i < 4; ++i) a[i] = As[ty * 4 + i][kk];
#pragma unroll
      for (int j = 0; j < 8; ++j) b[j] = Bs[kk][tx * 8 + j];
#pragma unroll
      for (int i = 0; i < 4; ++i)
#pragma unroll
        for (int j = 0; j < 8; ++j) acc[i][j] += a[i] * b[j];
    }
    __syncthreads();
  }
#pragma unroll
  for (int i = 0; i < 4; ++i) {
    int gr = r0 + ty * 4 + i;
    if (gr < n) {
      float h[8];
#pragma unroll
      for (int j = 0; j < 8; ++j) h[j] = acc[i][j] + bias[tx * 8 + j];
      uint4 o;
      o.x = (unsigned)__half_as_ushort(__float2half(h[0])) |
            ((unsigned)__half_as_ushort(__float2half(h[1])) << 16);
      o.y = (unsigned)__half_as_ushort(__float2half(h[2])) |
            ((unsigned)__half_as_ushort(__float2half(h[3])) << 16);
      o.z = (unsigned)__half_as_ushort(__float2half(h[4])) |
            ((unsigned)__half_as_ushort(__float2half(h[5])) << 16);
      o.w = (unsigned)__half_as_ushort(__float2half(h[6])) |
            ((unsigned)__half_as_ushort(__float2half(h[7])) << 16);
      *reinterpret_cast<uint4*>(&Hh[(size_t)gr * DH + tx * 8]) = o;
    }
  }
}

// Pull aggregation: one wave per dst row, lane d = feature d.
// Per-lane elist staging + shfl broadcast; per-block stats partials.
__global__ __launch_bounds__(256) void k_gather(
    const unsigned* __restrict__ elist, const int* __restrict__ rowstart,
    const __half* __restrict__ Hh, const float* __restrict__ sc,
    __half* __restrict__ AGGh, float* __restrict__ statp, int n) {
  const int wid = threadIdx.x >> 6;
  const int d = threadIdx.x & 63;
  const int gw = blockIdx.x * 4 + wid;
  const int nw = gridDim.x * 4;
  unsigned short* AGGu = (unsigned short*)AGGh;
  float s = 0.f, ss = 0.f;
  for (int row = gw; row < n; row += nw) {
    const int rs = rowstart[row], re = rowstart[row + 1];
    float acc = __half2float(Hh[(size_t)row * DH + d]) * sc[row];
    for (int base = rs; base < re; base += 64) {
      const int rem = re - base;                 // multiple of 8
      unsigned eL = 0u;
      if (d < rem) eL = __builtin_nontemporal_load(&elist[base + d]);
      const int m = rem < 64 ? rem : 64;         // multiple of 8
      for (int j = 0; j < m; j += 8) {
#pragma unroll
        for (int jj = 0; jj < 8; ++jj) {
          const unsigned e = __shfl(eL, j + jj, 64);
          const float v = __half2float(Hh[(size_t)(e & 0x1FFFFu) * DH + d]);
          const float nm =
              __half2float(__ushort_as_half((unsigned short)(e >> 17)));
          acc = fmaf(nm, v, acc);
        }
      }
    }
    __builtin_nontemporal_store(__half_as_ushort(__float2half(acc)),
                                &AGGu[(size_t)row * DH + d]);
    s += acc;
    ss += acc * acc;
  }
  __shared__ float sm[4][DH], sm2[4][DH];
  sm[wid][d] = s;
  sm2[wid][d] = ss;
  __syncthreads();
  if (threadIdx.x < DH) {
    float a = sm[0][d] + sm[1][d] + sm[2][d] + sm[3][d];
    float b = sm2[0][d] + sm2[1][d] + sm2[2][d] + sm2[3][d];
    __builtin_nontemporal_store(a, &statp[(size_t)blockIdx.x * 128 + d]);
    __builtin_nontemporal_store(b, &statp[(size_t)blockIdx.x * 128 + DH + d]);
  }
}

// reduce per-block stat partials: one block per stat entry (128 blocks)
__global__ __launch_bounds__(256) void k_redstats(const float* __restrict__ statp,
                                                  float* __restrict__ stats, int nblk) {
  const int t = blockIdx.x;   // 0..127
  float s = 0.f;
  for (int b = threadIdx.x; b < nblk; b += 256) s += statp[(size_t)b * 128 + t];
#pragma unroll
  for (int o = 32; o > 0; o >>= 1) s += __shfl_down(s, o, 64);
  __shared__ float sm[4];
  if ((threadIdx.x & 63) == 0) sm[threadIdx.x >> 6] = s;
  __syncthreads();
  if (threadIdx.x == 0) stats[t] = sm[0] + sm[1] + sm[2] + sm[3];
}

// fused BN+ReLU+mean-pool+head: one block per graph.
__global__ __launch_bounds__(256) void k_poolhead(
    const __half* __restrict__ AGGh, const float* __restrict__ stats,
    const float* __restrict__ gam, const float* __restrict__ bet,
    const float* __restrict__ ow, const int* __restrict__ gstart,
    const float* __restrict__ ob, float* __restrict__ out, float invN) {
  const int g = blockIdx.x;
  const int gs = gstart[g], ge = gstart[g + 1];
  const int wid = threadIdx.x >> 6;
  const int d = threadIdx.x & 63;
  float mean = stats[d] * invN;
  float var = stats[DH + d] * invN - mean * mean;
  float sa = rsqrtf(var + EPSV) * gam[d];
  float sb = bet[d] - mean * sa;
  const float w = ow[d];
  float acc = 0.f;
  for (int row = gs + wid; row < ge; row += 4)
    acc += fmaxf(__half2float(AGGh[(size_t)row * DH + d]) * sa + sb, 0.f) * w;
#pragma unroll
  for (int off = 32; off > 0; off >>= 1) acc += __shfl_down(acc, off, 64);
  __shared__ float sm[4];
  if (d == 0) sm[wid] = acc;
  __syncthreads();
  if (threadIdx.x == 0) {
    float s = sm[0] + sm[1] + sm[2] + sm[3];
    float cnt = (float)(ge - gs);
    out[g] = s / fmaxf(cnt, 1.0f) + ob[0];
  }
}

extern "C" void kernel_launch(void* const* d_in, const int* in_sizes, int n_in,
                              void* d_out, int out_size, void* d_ws, size_t ws_size,
                              hipStream_t stream) {
  const float* x    = (const float*)d_in[0];
  const int*   ei   = (const int*)d_in[1];
  const float* ew   = (const float*)d_in[2];
  const int*   batch= (const int*)d_in[3];
  const float* w0   = (const float*)d_in[4];
  const float* b0   = (const float*)d_in[5];
  const float* g0   = (const float*)d_in[6];
  const float* be0  = (const float*)d_in[7];
  const float* w1   = (const float*)d_in[8];
  const float* b1   = (const float*)d_in[9];
  const float* g1   = (const float*)d_in[10];
  const float* be1  = (const float*)d_in[11];
  const float* w2   = (const float*)d_in[12];
  const float* b2   = (const float*)d_in[13];
  const float* g2   = (const float*)d_in[14];
  const float* be2  = (const float*)d_in[15];
  const float* ow   = (const float*)d_in[16];
  const float* ob   = (const float*)d_in[17];

  const int N_  = in_sizes[3];
  const int E_  = in_sizes[2];
  const int DIN_= in_sizes[0] / N_;
  const int G_  = out_size;
  const int* srcIdx = ei;
  const int* dstIdx = ei + E_;
  const int n1 = N_ + 1;
  const size_t epad = (size_t)E_ + 7ull * N_;   // max padded edge slots

  float* ws = (float*)d_ws;
  size_t off = 0;
  unsigned long long* bstage = (unsigned long long*)(ws + off);
  off += (size_t)2 * NBUK * CAP;                     // NBUK*CAP u64
  unsigned* elist = (unsigned*)(ws + off); off += epad;
  float* dinv     = ws + off; off += N_;
  float* sc       = ws + off; off += N_;
  int*   cnt      = (int*)(ws + off); off += N_;
  int*   rowstart = (int*)(ws + off); off += n1 + 1;
  int*   bsums    = (int*)(ws + off); off += 256;
  unsigned* gcur0 = (unsigned*)(ws + off); off += NBUK;
  int*   gstart   = (int*)(ws + off); off += G_ + 1;
  __half* hhalf   = (__half*)(ws + off); off += (size_t)N_ * DH / 2;
  __half* aggh    = (__half*)(ws + off); off += (size_t)N_ * DH / 2;
  float* stats    = ws + off; off += 2 * DH;
  float* statp    = ws + off; off += (size_t)GBLK * 128;
  (void)ws_size; (void)n_in;

  // --- binned CSR build (histogram derived from bins; no global atomics on N) ---
  k_gcur0<<<1, NBUK, 0, stream>>>(gcur0);
  k_bin0<<<(E_ + 256 * BINJ - 1) / (256 * BINJ), 256, 0, stream>>>(
      srcIdx, dstIdx, ew, gcur0, bstage, E_);
  k_bcnt<<<NBUK, 256, 0, stream>>>(bstage, gcur0, cnt, dinv, sc, N_);

  const int nb = (n1 + 1023) / 1024;
  k_scan1<<<nb, 256, 0, stream>>>(cnt, rowstart, bsums, N_, n1);
  k_scan2<<<1, 256, 0, stream>>>(bsums, nb);
  k_scan3<<<(n1 + 255) / 256, 256, 0, stream>>>(rowstart, bsums, n1);

  k_fin<<<NBUK, 256, 0, stream>>>(bstage, rowstart, gcur0, dinv, elist, N_);

  // --- graph boundaries for pooling ---
  k_gbound<<<(N_ + 255) / 256, 256, 0, stream>>>(batch, gstart, N_, G_);

  const float* Wl[3]  = {w0, w1, w2};
  const float* Bl[3]  = {b0, b1, b2};
  const float* Gl[3]  = {g0, g1, g2};
  const float* BeL[3] = {be0, be1, be2};

  const float invN = 1.0f / (float)N_;

  for (int l = 0; l < 3; ++l) {
    if (l == 0) {
      k_gemm<float><<<(N_ + 127) / 128, 256, 0, stream>>>(
          x, Wl[0], Bl[0], stats, nullptr, nullptr, hhalf, N_, DIN_, 0, invN);
    } else {
      k_gemm<__half><<<(N_ + 127) / 128, 256, 0, stream>>>(
          aggh, Wl[l], Bl[l], stats, Gl[l - 1], BeL[l - 1], hhalf, N_, DH, 1, invN);
    }
    k_gather<<<GBLK, 256, 0, stream>>>(elist, rowstart, hhalf, sc, aggh, statp, N_);
    k_redstats<<<128, 256, 0, stream>>>(statp, stats, GBLK);
  }

  // --- fused BN2+ReLU+pooling+head ---
  k_poolhead<<<G_, 256, 0, stream>>>(aggh, stats, g2, be2, ow, gstart, ob,
                                     (float*)d_out, invN);
}

// Round 12
// 373.606 us; speedup vs baseline: 1.6923x; 1.0306x over previous
//
#include <hip/hip_runtime.h>
#include <hip/hip_fp16.h>
#include <cstdint>

#define DH 64
#define EPSV 1e-5f
#define GBLK 2048
#define NBUK 256
#define BROWS 512
#define BINJ 8
#define CAP 12288

typedef _Float16 half8 __attribute__((ext_vector_type(8)));
typedef float f32x4 __attribute__((ext_vector_type(4)));

__global__ void k_fill(float* __restrict__ p, float v, size_t n) {
  size_t i = blockIdx.x * (size_t)blockDim.x + threadIdx.x;
  if (i < n) p[i] = v;
}

// init bucket stage cursors: gcur0[b] = b*CAP
__global__ void k_gcur0(unsigned* __restrict__ gcur0) {
  gcur0[threadIdx.x] = (unsigned)(threadIdx.x * CAP);
}

// Pass 1: bin edges by dst bucket (no dinv dependency).
// payload u64: hi = (dst&511)<<17 | src, lo = fp32 ew bits.
__global__ __launch_bounds__(256) void k_bin0(
    const int* __restrict__ src, const int* __restrict__ dst,
    const float* __restrict__ ew, unsigned* __restrict__ gcur0,
    unsigned long long* __restrict__ bstage, int E_) {
  __shared__ unsigned cntL[NBUK], offL[NBUK], runL[NBUK];
  const int t = threadIdx.x;
  const int base = blockIdx.x * (256 * BINJ);
  cntL[t] = 0;
  runL[t] = 0;
  __syncthreads();
  unsigned hi[BINJ], lo[BINJ];
  int bb[BINJ];
#pragma unroll
  for (int j = 0; j < BINJ; ++j) {
    int e = base + j * 256 + t;
    bb[j] = -1;
    if (e < E_) {
      int q = dst[e];
      hi[j] = ((unsigned)(q & (BROWS - 1)) << 17) | (unsigned)src[e];
      lo[j] = __float_as_uint(ew[e]);
      bb[j] = q >> 9;
      atomicAdd(&cntL[bb[j]], 1u);
    }
  }
  __syncthreads();
  offL[t] = cntL[t] ? atomicAdd(&gcur0[t], cntL[t]) : 0u;
  __syncthreads();
#pragma unroll
  for (int j = 0; j < BINJ; ++j) {
    if (bb[j] >= 0) {
      unsigned p = offL[bb[j]] + atomicAdd(&runL[bb[j]], 1u);
      bstage[p] = ((unsigned long long)hi[j] << 32) | lo[j];
    }
  }
}

// Per-bucket histogram from staged runs: cnt, dinv, sc (deterministic:
// integer LDS atomics, fixed-point 2^-24 ew sum; deg includes +1 self-loop).
__global__ __launch_bounds__(256) void k_bcnt(
    const unsigned long long* __restrict__ bstage, const unsigned* __restrict__ gcur0,
    int* __restrict__ cnt, float* __restrict__ dinv, float* __restrict__ sc, int N_) {
  __shared__ unsigned cntL[BROWS], degL[BROWS];
  const int b = blockIdx.x, t = threadIdx.x;
  for (int i = t; i < BROWS; i += 256) {
    cntL[i] = 0;
    degL[i] = 0;
  }
  __syncthreads();
  const unsigned beg = (unsigned)(b * CAP), end = gcur0[b];
  for (unsigned p = beg + t; p < end; p += 256) {
    unsigned long long v = bstage[p];
    unsigned r = (unsigned)(v >> 49);                 // dst_local
    float w = __uint_as_float((unsigned)v);
    atomicAdd(&cntL[r], 1u);
    atomicAdd(&degL[r], (unsigned)(w * 16777216.0f));
  }
  __syncthreads();
  for (int i = t; i < BROWS; i += 256) {
    int r = b * BROWS + i;
    if (r < N_) {
      float deg = 1.0f + (float)degL[i] * (1.0f / 16777216.0f);
      cnt[r] = (int)cntL[i];
      dinv[r] = rsqrtf(deg);
      sc[r] = 1.0f / deg;
    }
  }
}

// ---- exclusive scan over n1 = N+1 values; value(i) = i<N ? pad8(cnt[i]) : 0 ----
__global__ __launch_bounds__(256) void k_scan1(const int* __restrict__ cnt,
                                               int* __restrict__ out,
                                               int* __restrict__ bsums,
                                               int N_, int n1) {
  __shared__ int sm[256];
  const int t = threadIdx.x;
  const int base = blockIdx.x * 1024 + t * 4;
  int v[4], lsum = 0;
#pragma unroll
  for (int j = 0; j < 4; ++j) {
    int i = base + j;
    v[j] = (i < N_) ? ((cnt[i] + 7) & ~7) : 0;   // pad rows to multiple of 8
    lsum += v[j];
  }
  sm[t] = lsum;
  __syncthreads();
  for (int o = 1; o < 256; o <<= 1) {
    int x = (t >= o) ? sm[t - o] : 0;
    __syncthreads();
    if (t >= o) sm[t] += x;
    __syncthreads();
  }
  int run = sm[t] - lsum;
#pragma unroll
  for (int j = 0; j < 4; ++j) {
    int i = base + j;
    if (i < n1) out[i] = run;
    run += v[j];
  }
  if (t == 255) bsums[blockIdx.x] = sm[255];
}

__global__ __launch_bounds__(256) void k_scan2(int* __restrict__ bsums, int nb) {
  __shared__ int sm[256];
  int t = threadIdx.x;
  int v = (t < nb) ? bsums[t] : 0;
  sm[t] = v;
  __syncthreads();
  for (int o = 1; o < 256; o <<= 1) {
    int x = (t >= o) ? sm[t - o] : 0;
    __syncthreads();
    if (t >= o) sm[t] += x;
    __syncthreads();
  }
  if (t < nb) bsums[t] = sm[t] - v;
}

__global__ void k_scan3(int* __restrict__ out, const int* __restrict__ bsums, int n1) {
  int i = blockIdx.x * blockDim.x + threadIdx.x;
  if (i < n1) out[i] += bsums[i >> 10];
}

// Pass 2: one block per bucket; compute norm + place into CSR slots via LDS
// cursors; fill pad slots from the same cursors (all writes L2-window-local).
__global__ __launch_bounds__(256) void k_fin(
    const unsigned long long* __restrict__ bstage, const int* __restrict__ rowstart,
    const unsigned* __restrict__ gcur0, const float* __restrict__ dinv,
    unsigned* __restrict__ elist, int N_) {
  __shared__ unsigned lcur[BROWS];
  __shared__ int rsL[BROWS + 1];
  __shared__ float dvL[BROWS];
  const int b = blockIdx.x, t = threadIdx.x;
  const int r0 = b * BROWS;
  for (int i = t; i < BROWS; i += 256) {
    lcur[i] = 0;
    int r = r0 + i;
    dvL[i] = (r < N_) ? dinv[r] : 0.f;
  }
  for (int i = t; i <= BROWS; i += 256) {
    int r = r0 + i;
    if (r > N_) r = N_;
    rsL[i] = rowstart[r];
  }
  __syncthreads();
  const unsigned beg = (unsigned)(b * CAP), end = gcur0[b];
  for (unsigned p = beg + t; p < end; p += 256) {
    unsigned long long v = bstage[p];
    unsigned hi = (unsigned)(v >> 32);
    unsigned r = hi >> 17;
    unsigned s = hi & 0x1FFFFu;
    float w = __uint_as_float((unsigned)v);
    float nm = w * dinv[s] * dvL[r];
    unsigned h15 = (unsigned)__half_as_ushort(__float2half(nm));
    unsigned slot = (unsigned)rsL[r] + atomicAdd(&lcur[r], 1u);
    elist[slot] = (h15 << 17) | s;
  }
  __syncthreads();
  for (int i = t; i < BROWS; i += 256) {
    unsigned p = (unsigned)rsL[i] + lcur[i];
    const unsigned pe = (unsigned)rsL[i + 1];
    for (; p < pe; ++p) elist[p] = 0u;
  }
}

// graph boundary detection on sorted batch: gstart[g] for g in [0,G]
__global__ void k_gbound(const int* __restrict__ batch, int* __restrict__ gstart,
                         int N_, int G_) {
  int i = blockIdx.x * blockDim.x + threadIdx.x;
  if (i >= N_) return;
  int b = batch[i];
  if (i == 0) {
    for (int g = 0; g <= b; ++g) gstart[g] = 0;
  }
  int nb = (i + 1 < N_) ? batch[i + 1] : G_;
  for (int g = b + 1; g <= nb; ++g) gstart[g] = i + 1;
}

// MFMA GEMM: 128 rows x 64 cols per block, 4 waves x (32 rows x 64 cols).
// mfma_f32_16x16x32_f16; A & B^T staged to LDS fp16 with XOR swizzle
// (k0 ^ ((row&7)*8) halves) -> conflict-light ds_read_b128 frags.
// FUSE: BN(prev)+ReLU applied to A during staging. Writes fp16 H.
template <int KP, int FUSE>
__global__ __launch_bounds__(256) void k_gemm_mfma(
    const void* __restrict__ Ap, const float* __restrict__ W,
    const float* __restrict__ bias, const float* __restrict__ stats,
    const float* __restrict__ gam, const float* __restrict__ bet,
    __half* __restrict__ Hh, int n, int Kreal, float invN) {
  __shared__ _Float16 Ah[128 * KP];
  __shared__ _Float16 Bt[64 * KP];
  __shared__ float saL[DH], sbL[DH];
  const int tid = threadIdx.x;
  const int r0 = blockIdx.x * 128;
  if (FUSE) {
    if (tid < DH) {
      float mean = stats[tid] * invN;
      float var = stats[DH + tid] * invN - mean * mean;
      float a = rsqrtf(var + EPSV) * gam[tid];
      saL[tid] = a;
      sbL[tid] = bet[tid] - mean * a;
    }
    __syncthreads();
  }
  constexpr int KC = KP / 8;
  // stage A (fp32 x or fp16 agg + BN/ReLU) -> fp16 LDS, swizzled
  for (int ci = tid; ci < 128 * KC; ci += 256) {
    int row = ci / KC, kc = ci % KC;
    int gr = r0 + row, k0 = kc * 8;
    half8 hv;
    if (FUSE) {
      const unsigned short* Aa = (const unsigned short*)Ap;
#pragma unroll
      for (int j = 0; j < 8; ++j) {
        int k = k0 + j;
        float a = (gr < n) ? __half2float(__ushort_as_half(Aa[(size_t)gr * DH + k])) : 0.f;
        hv[j] = (_Float16)fmaxf(a * saL[k] + sbL[k], 0.f);
      }
    } else {
      const float* Ax = (const float*)Ap;
#pragma unroll
      for (int j = 0; j < 8; ++j) {
        int k = k0 + j;
        float a = (gr < n && k < Kreal) ? Ax[(size_t)gr * Kreal + k] : 0.f;
        hv[j] = (_Float16)a;
      }
    }
    *(half8*)&Ah[row * KP + (k0 ^ ((row & 7) * 8))] = hv;
  }
  // stage B transposed: Bt[c][k] = W[k][c]
  for (int ci = tid; ci < 64 * KC; ci += 256) {
    int c = ci / KC, kc = ci % KC, k0 = kc * 8;
    half8 wv;
#pragma unroll
    for (int j = 0; j < 8; ++j) {
      int k = k0 + j;
      wv[j] = (_Float16)((k < Kreal) ? W[k * DH + c] : 0.f);
    }
    *(half8*)&Bt[c * KP + (k0 ^ ((c & 7) * 8))] = wv;
  }
  __syncthreads();
  const int w = tid >> 6, l = tid & 63;
  const int lr = l & 15, lg = l >> 4;
  f32x4 acc[2][4];
#pragma unroll
  for (int a1 = 0; a1 < 2; ++a1)
#pragma unroll
    for (int a2 = 0; a2 < 4; ++a2) acc[a1][a2] = (f32x4){0.f, 0.f, 0.f, 0.f};
#pragma unroll
  for (int ks = 0; ks < KP / 32; ++ks) {
    const int k0 = ks * 32 + lg * 8;
    half8 av[2], bv[4];
#pragma unroll
    for (int rf = 0; rf < 2; ++rf) {
      int row = w * 32 + rf * 16 + lr;
      av[rf] = *(const half8*)&Ah[row * KP + (k0 ^ ((row & 7) * 8))];
    }
#pragma unroll
    for (int cf = 0; cf < 4; ++cf) {
      int col = cf * 16 + lr;
      bv[cf] = *(const half8*)&Bt[col * KP + (k0 ^ ((col & 7) * 8))];
    }
#pragma unroll
    for (int rf = 0; rf < 2; ++rf)
#pragma unroll
      for (int cf = 0; cf < 4; ++cf)
        acc[rf][cf] =
            __builtin_amdgcn_mfma_f32_16x16x32_f16(av[rf], bv[cf], acc[rf][cf], 0, 0, 0);
  }
  // epilogue: C/D layout col=lane&15, row=(lane>>4)*4+i
  unsigned short* Hu = (unsigned short*)Hh;
#pragma unroll
  for (int rf = 0; rf < 2; ++rf) {
#pragma unroll
    for (int cf = 0; cf < 4; ++cf) {
      int col = cf * 16 + lr;
      float bcol = bias[col];
#pragma unroll
      for (int i = 0; i < 4; ++i) {
        int row = r0 + w * 32 + rf * 16 + lg * 4 + i;
        if (row < n)
          Hu[(size_t)row * DH + col] = __half_as_ushort(__float2half(acc[rf][cf][i] + bcol));
      }
    }
  }
}

// Pull aggregation: one wave per dst row, lane d = feature d.
// Per-lane elist staging + shfl broadcast; per-block stats partials.
__global__ __launch_bounds__(256) void k_gather(
    const unsigned* __restrict__ elist, const int* __restrict__ rowstart,
    const __half* __restrict__ Hh, const float* __restrict__ sc,
    __half* __restrict__ AGGh, float* __restrict__ statp, int n) {
  const int wid = threadIdx.x >> 6;
  const int d = threadIdx.x & 63;
  const int gw = blockIdx.x * 4 + wid;
  const int nw = gridDim.x * 4;
  unsigned short* AGGu = (unsigned short*)AGGh;
  float s = 0.f, ss = 0.f;
  for (int row = gw; row < n; row += nw) {
    const int rs = rowstart[row], re = rowstart[row + 1];
    float acc = __half2float(Hh[(size_t)row * DH + d]) * sc[row];
    for (int base = rs; base < re; base += 64) {
      const int rem = re - base;                 // multiple of 8
      unsigned eL = 0u;
      if (d < rem) eL = __builtin_nontemporal_load(&elist[base + d]);
      const int m = rem < 64 ? rem : 64;         // multiple of 8
      for (int j = 0; j < m; j += 8) {
#pragma unroll
        for (int jj = 0; jj < 8; ++jj) {
          const unsigned e = __shfl(eL, j + jj, 64);
          const float v = __half2float(Hh[(size_t)(e & 0x1FFFFu) * DH + d]);
          const float nm =
              __half2float(__ushort_as_half((unsigned short)(e >> 17)));
          acc = fmaf(nm, v, acc);
        }
      }
    }
    __builtin_nontemporal_store(__half_as_ushort(__float2half(acc)),
                                &AGGu[(size_t)row * DH + d]);
    s += acc;
    ss += acc * acc;
  }
  __shared__ float sm[4][DH], sm2[4][DH];
  sm[wid][d] = s;
  sm2[wid][d] = ss;
  __syncthreads();
  if (threadIdx.x < DH) {
    float a = sm[0][d] + sm[1][d] + sm[2][d] + sm[3][d];
    float b = sm2[0][d] + sm2[1][d] + sm2[2][d] + sm2[3][d];
    __builtin_nontemporal_store(a, &statp[(size_t)blockIdx.x * 128 + d]);
    __builtin_nontemporal_store(b, &statp[(size_t)blockIdx.x * 128 + DH + d]);
  }
}

// reduce per-block stat partials: one block per stat entry (128 blocks)
__global__ __launch_bounds__(256) void k_redstats(const float* __restrict__ statp,
                                                  float* __restrict__ stats, int nblk) {
  const int t = blockIdx.x;   // 0..127
  float s = 0.f;
  for (int b = threadIdx.x; b < nblk; b += 256) s += statp[(size_t)b * 128 + t];
#pragma unroll
  for (int o = 32; o > 0; o >>= 1) s += __shfl_down(s, o, 64);
  __shared__ float sm[4];
  if ((threadIdx.x & 63) == 0) sm[threadIdx.x >> 6] = s;
  __syncthreads();
  if (threadIdx.x == 0) stats[t] = sm[0] + sm[1] + sm[2] + sm[3];
}

// fused BN+ReLU+mean-pool+head: one block per graph.
__global__ __launch_bounds__(256) void k_poolhead(
    const __half* __restrict__ AGGh, const float* __restrict__ stats,
    const float* __restrict__ gam, const float* __restrict__ bet,
    const float* __restrict__ ow, const int* __restrict__ gstart,
    const float* __restrict__ ob, float* __restrict__ out, float invN) {
  const int g = blockIdx.x;
  const int gs = gstart[g], ge = gstart[g + 1];
  const int wid = threadIdx.x >> 6;
  const int d = threadIdx.x & 63;
  float mean = stats[d] * invN;
  float var = stats[DH + d] * invN - mean * mean;
  float sa = rsqrtf(var + EPSV) * gam[d];
  float sb = bet[d] - mean * sa;
  const float w = ow[d];
  float acc = 0.f;
  for (int row = gs + wid; row < ge; row += 4)
    acc += fmaxf(__half2float(AGGh[(size_t)row * DH + d]) * sa + sb, 0.f) * w;
#pragma unroll
  for (int off = 32; off > 0; off >>= 1) acc += __shfl_down(acc, off, 64);
  __shared__ float sm[4];
  if (d == 0) sm[wid] = acc;
  __syncthreads();
  if (threadIdx.x == 0) {
    float s = sm[0] + sm[1] + sm[2] + sm[3];
    float cnt = (float)(ge - gs);
    out[g] = s / fmaxf(cnt, 1.0f) + ob[0];
  }
}

extern "C" void kernel_launch(void* const* d_in, const int* in_sizes, int n_in,
                              void* d_out, int out_size, void* d_ws, size_t ws_size,
                              hipStream_t stream) {
  const float* x    = (const float*)d_in[0];
  const int*   ei   = (const int*)d_in[1];
  const float* ew   = (const float*)d_in[2];
  const int*   batch= (const int*)d_in[3];
  const float* w0   = (const float*)d_in[4];
  const float* b0   = (const float*)d_in[5];
  const float* g0   = (const float*)d_in[6];
  const float* be0  = (const float*)d_in[7];
  const float* w1   = (const float*)d_in[8];
  const float* b1   = (const float*)d_in[9];
  const float* g1   = (const float*)d_in[10];
  const float* be1  = (const float*)d_in[11];
  const float* w2   = (const float*)d_in[12];
  const float* b2   = (const float*)d_in[13];
  const float* g2   = (const float*)d_in[14];
  const float* be2  = (const float*)d_in[15];
  const float* ow   = (const float*)d_in[16];
  const float* ob   = (const float*)d_in[17];

  const int N_  = in_sizes[3];
  const int E_  = in_sizes[2];
  const int DIN_= in_sizes[0] / N_;
  const int G_  = out_size;
  const int* srcIdx = ei;
  const int* dstIdx = ei + E_;
  const int n1 = N_ + 1;
  const size_t epad = (size_t)E_ + 7ull * N_;   // max padded edge slots

  float* ws = (float*)d_ws;
  size_t off = 0;
  unsigned long long* bstage = (unsigned long long*)(ws + off);
  off += (size_t)2 * NBUK * CAP;                     // NBUK*CAP u64
  unsigned* elist = (unsigned*)(ws + off); off += epad;
  float* dinv     = ws + off; off += N_;
  float* sc       = ws + off; off += N_;
  int*   cnt      = (int*)(ws + off); off += N_;
  int*   rowstart = (int*)(ws + off); off += n1 + 1;
  int*   bsums    = (int*)(ws + off); off += 256;
  unsigned* gcur0 = (unsigned*)(ws + off); off += NBUK;
  int*   gstart   = (int*)(ws + off); off += G_ + 1;
  __half* hhalf   = (__half*)(ws + off); off += (size_t)N_ * DH / 2;
  __half* aggh    = (__half*)(ws + off); off += (size_t)N_ * DH / 2;
  float* stats    = ws + off; off += 2 * DH;
  float* statp    = ws + off; off += (size_t)GBLK * 128;
  (void)ws_size; (void)n_in;

  // --- binned CSR build ---
  k_gcur0<<<1, NBUK, 0, stream>>>(gcur0);
  k_bin0<<<(E_ + 256 * BINJ - 1) / (256 * BINJ), 256, 0, stream>>>(
      srcIdx, dstIdx, ew, gcur0, bstage, E_);
  k_bcnt<<<NBUK, 256, 0, stream>>>(bstage, gcur0, cnt, dinv, sc, N_);

  const int nb = (n1 + 1023) / 1024;
  k_scan1<<<nb, 256, 0, stream>>>(cnt, rowstart, bsums, N_, n1);
  k_scan2<<<1, 256, 0, stream>>>(bsums, nb);
  k_scan3<<<(n1 + 255) / 256, 256, 0, stream>>>(rowstart, bsums, n1);

  k_fin<<<NBUK, 256, 0, stream>>>(bstage, rowstart, gcur0, dinv, elist, N_);

  // --- graph boundaries for pooling ---
  k_gbound<<<(N_ + 255) / 256, 256, 0, stream>>>(batch, gstart, N_, G_);

  const float* Wl[3]  = {w0, w1, w2};
  const float* Bl[3]  = {b0, b1, b2};
  const float* Gl[3]  = {g0, g1, g2};
  const float* BeL[3] = {be0, be1, be2};

  const float invN = 1.0f / (float)N_;
  const int gblk = (N_ + 127) / 128;

  for (int l = 0; l < 3; ++l) {
    if (l == 0) {
      k_gemm_mfma<128, 0><<<gblk, 256, 0, stream>>>(
          (const void*)x, Wl[0], Bl[0], stats, nullptr, nullptr, hhalf, N_, DIN_, invN);
    } else {
      k_gemm_mfma<64, 1><<<gblk, 256, 0, stream>>>(
          (const void*)aggh, Wl[l], Bl[l], stats, Gl[l - 1], BeL[l - 1], hhalf, N_, DH, invN);
    }
    k_gather<<<GBLK, 256, 0, stream>>>(elist, rowstart, hhalf, sc, aggh, statp, N_);
    k_redstats<<<128, 256, 0, stream>>>(statp, stats, GBLK);
  }

  // --- fused BN2+ReLU+pooling+head ---
  k_poolhead<<<G_, 256, 0, stream>>>(aggh, stats, g2, be2, ow, gstart, ob,
                                     (float*)d_out, invN);
}

// Round 13
// 338.212 us; speedup vs baseline: 1.8694x; 1.1047x over previous
//
#include <hip/hip_runtime.h>
#include <hip/hip_fp16.h>
#include <cstdint>

#define DH 64
#define EPSV 1e-5f
#define GBLK 2048
#define NBUK 256
#define BROWS 512
#define BINJ 8
#define CAP 12288

typedef _Float16 half8 __attribute__((ext_vector_type(8)));
typedef float f32x4 __attribute__((ext_vector_type(4)));

__global__ void k_fill(float* __restrict__ p, float v, size_t n) {
  size_t i = blockIdx.x * (size_t)blockDim.x + threadIdx.x;
  if (i < n) p[i] = v;
}

// init bucket stage cursors: gcur0[b] = b*CAP
__global__ void k_gcur0(unsigned* __restrict__ gcur0) {
  gcur0[threadIdx.x] = (unsigned)(threadIdx.x * CAP);
}

// x (fp32 [N][100]) -> xh (fp16 [N][128], zero-padded). float4-coalesced.
__global__ __launch_bounds__(256) void k_xhalf(const float* __restrict__ x,
                                               unsigned short* __restrict__ xh,
                                               int N_, int K) {
  const int cpr = K / 4;                       // f4 chunks per row (25)
  size_t i = blockIdx.x * 256ull + threadIdx.x;
  if (i >= (size_t)N_ * cpr) return;
  int row = (int)(i / cpr), c0 = (int)(i % cpr) * 4;
  float4 v = *(const float4*)&x[(size_t)row * K + c0];
  ushort4 h;
  h.x = __half_as_ushort(__float2half(v.x));
  h.y = __half_as_ushort(__float2half(v.y));
  h.z = __half_as_ushort(__float2half(v.z));
  h.w = __half_as_ushort(__float2half(v.w));
  *(ushort4*)&xh[(size_t)row * 128 + c0] = h;
  if (c0 == K - 4) {                           // pad K..127 with zeros
    ushort4 z4 = {0, 0, 0, 0};
    uint4 z16 = {0, 0, 0, 0};
    *(ushort4*)&xh[(size_t)row * 128 + K] = z4;          // 100..103
    *(uint4*)&xh[(size_t)row * 128 + K + 4] = z16;       // 104..111
    *(uint4*)&xh[(size_t)row * 128 + K + 12] = z16;      // 112..119
    *(uint4*)&xh[(size_t)row * 128 + K + 20] = z16;      // 120..127
  }
}

// W (fp32 [Kreal][64]) -> wt (fp16 [64][KP], zero-padded transpose)
__global__ void k_wt(const float* __restrict__ W, unsigned short* __restrict__ wt,
                     int Kreal, int KP) {
  int idx = blockIdx.x * 256 + threadIdx.x;
  if (idx >= 64 * KP) return;
  int c = idx / KP, k = idx % KP;
  float v = (k < Kreal) ? W[k * DH + c] : 0.f;
  wt[idx] = __half_as_ushort(__float2half(v));
}

// Pass 1: bin edges by dst bucket (no dinv dependency).
// payload u64: hi = (dst&511)<<17 | src, lo = fp32 ew bits.
__global__ __launch_bounds__(256) void k_bin0(
    const int* __restrict__ src, const int* __restrict__ dst,
    const float* __restrict__ ew, unsigned* __restrict__ gcur0,
    unsigned long long* __restrict__ bstage, int E_) {
  __shared__ unsigned cntL[NBUK], offL[NBUK], runL[NBUK];
  const int t = threadIdx.x;
  const int base = blockIdx.x * (256 * BINJ);
  cntL[t] = 0;
  runL[t] = 0;
  __syncthreads();
  unsigned hi[BINJ], lo[BINJ];
  int bb[BINJ];
#pragma unroll
  for (int j = 0; j < BINJ; ++j) {
    int e = base + j * 256 + t;
    bb[j] = -1;
    if (e < E_) {
      int q = dst[e];
      hi[j] = ((unsigned)(q & (BROWS - 1)) << 17) | (unsigned)src[e];
      lo[j] = __float_as_uint(ew[e]);
      bb[j] = q >> 9;
      atomicAdd(&cntL[bb[j]], 1u);
    }
  }
  __syncthreads();
  offL[t] = cntL[t] ? atomicAdd(&gcur0[t], cntL[t]) : 0u;
  __syncthreads();
#pragma unroll
  for (int j = 0; j < BINJ; ++j) {
    if (bb[j] >= 0) {
      unsigned p = offL[bb[j]] + atomicAdd(&runL[bb[j]], 1u);
      bstage[p] = ((unsigned long long)hi[j] << 32) | lo[j];
    }
  }
}

// Per-bucket histogram from staged runs: cnt, dinv, sc (deterministic).
__global__ __launch_bounds__(256) void k_bcnt(
    const unsigned long long* __restrict__ bstage, const unsigned* __restrict__ gcur0,
    int* __restrict__ cnt, float* __restrict__ dinv, float* __restrict__ sc, int N_) {
  __shared__ unsigned cntL[BROWS], degL[BROWS];
  const int b = blockIdx.x, t = threadIdx.x;
  for (int i = t; i < BROWS; i += 256) {
    cntL[i] = 0;
    degL[i] = 0;
  }
  __syncthreads();
  const unsigned beg = (unsigned)(b * CAP), end = gcur0[b];
  for (unsigned p = beg + t; p < end; p += 256) {
    unsigned long long v = bstage[p];
    unsigned r = (unsigned)(v >> 49);
    float w = __uint_as_float((unsigned)v);
    atomicAdd(&cntL[r], 1u);
    atomicAdd(&degL[r], (unsigned)(w * 16777216.0f));
  }
  __syncthreads();
  for (int i = t; i < BROWS; i += 256) {
    int r = b * BROWS + i;
    if (r < N_) {
      float deg = 1.0f + (float)degL[i] * (1.0f / 16777216.0f);
      cnt[r] = (int)cntL[i];
      dinv[r] = rsqrtf(deg);
      sc[r] = 1.0f / deg;
    }
  }
}

// ---- exclusive scan over n1 = N+1 values; value(i) = i<N ? pad8(cnt[i]) : 0 ----
__global__ __launch_bounds__(256) void k_scan1(const int* __restrict__ cnt,
                                               int* __restrict__ out,
                                               int* __restrict__ bsums,
                                               int N_, int n1) {
  __shared__ int sm[256];
  const int t = threadIdx.x;
  const int base = blockIdx.x * 1024 + t * 4;
  int v[4], lsum = 0;
#pragma unroll
  for (int j = 0; j < 4; ++j) {
    int i = base + j;
    v[j] = (i < N_) ? ((cnt[i] + 7) & ~7) : 0;
    lsum += v[j];
  }
  sm[t] = lsum;
  __syncthreads();
  for (int o = 1; o < 256; o <<= 1) {
    int x = (t >= o) ? sm[t - o] : 0;
    __syncthreads();
    if (t >= o) sm[t] += x;
    __syncthreads();
  }
  int run = sm[t] - lsum;
#pragma unroll
  for (int j = 0; j < 4; ++j) {
    int i = base + j;
    if (i < n1) out[i] = run;
    run += v[j];
  }
  if (t == 255) bsums[blockIdx.x] = sm[255];
}

__global__ __launch_bounds__(256) void k_scan2(int* __restrict__ bsums, int nb) {
  __shared__ int sm[256];
  int t = threadIdx.x;
  int v = (t < nb) ? bsums[t] : 0;
  sm[t] = v;
  __syncthreads();
  for (int o = 1; o < 256; o <<= 1) {
    int x = (t >= o) ? sm[t - o] : 0;
    __syncthreads();
    if (t >= o) sm[t] += x;
    __syncthreads();
  }
  if (t < nb) bsums[t] = sm[t] - v;
}

__global__ void k_scan3(int* __restrict__ out, const int* __restrict__ bsums, int n1) {
  int i = blockIdx.x * blockDim.x + threadIdx.x;
  if (i < n1) out[i] += bsums[i >> 10];
}

// Pass 2: one block per bucket; norm + CSR placement via LDS cursors.
__global__ __launch_bounds__(256) void k_fin(
    const unsigned long long* __restrict__ bstage, const int* __restrict__ rowstart,
    const unsigned* __restrict__ gcur0, const float* __restrict__ dinv,
    unsigned* __restrict__ elist, int N_) {
  __shared__ unsigned lcur[BROWS];
  __shared__ int rsL[BROWS + 1];
  __shared__ float dvL[BROWS];
  const int b = blockIdx.x, t = threadIdx.x;
  const int r0 = b * BROWS;
  for (int i = t; i < BROWS; i += 256) {
    lcur[i] = 0;
    int r = r0 + i;
    dvL[i] = (r < N_) ? dinv[r] : 0.f;
  }
  for (int i = t; i <= BROWS; i += 256) {
    int r = r0 + i;
    if (r > N_) r = N_;
    rsL[i] = rowstart[r];
  }
  __syncthreads();
  const unsigned beg = (unsigned)(b * CAP), end = gcur0[b];
  for (unsigned p = beg + t; p < end; p += 256) {
    unsigned long long v = bstage[p];
    unsigned hi = (unsigned)(v >> 32);
    unsigned r = hi >> 17;
    unsigned s = hi & 0x1FFFFu;
    float w = __uint_as_float((unsigned)v);
    float nm = w * dinv[s] * dvL[r];
    unsigned h15 = (unsigned)__half_as_ushort(__float2half(nm));
    unsigned slot = (unsigned)rsL[r] + atomicAdd(&lcur[r], 1u);
    elist[slot] = (h15 << 17) | s;
  }
  __syncthreads();
  for (int i = t; i < BROWS; i += 256) {
    unsigned p = (unsigned)rsL[i] + lcur[i];
    const unsigned pe = (unsigned)rsL[i + 1];
    for (; p < pe; ++p) elist[p] = 0u;
  }
}

// graph boundary detection on sorted batch: gstart[g] for g in [0,G]
__global__ void k_gbound(const int* __restrict__ batch, int* __restrict__ gstart,
                         int N_, int G_) {
  int i = blockIdx.x * blockDim.x + threadIdx.x;
  if (i >= N_) return;
  int b = batch[i];
  if (i == 0) {
    for (int g = 0; g <= b; ++g) gstart[g] = 0;
  }
  int nb = (i + 1 < N_) ? batch[i + 1] : G_;
  for (int g = b + 1; g <= nb; ++g) gstart[g] = i + 1;
}

// MFMA GEMM: 128x64/block, 4 waves x (32x64). All-fp16 operands, all staging
// via 16B vector loads. A stride = KP (xh padded 128 / aggh 64).
// FUSE: BN(prev)+ReLU applied to A during staging. Writes fp16 H.
template <int KP, int FUSE>
__global__ __launch_bounds__(256) void k_gemm_mfma(
    const unsigned short* __restrict__ Aa, const unsigned short* __restrict__ wt,
    const float* __restrict__ bias, const float* __restrict__ stats,
    const float* __restrict__ gam, const float* __restrict__ bet,
    __half* __restrict__ Hh, int n, float invN) {
  __shared__ unsigned short Ah[128 * KP];
  __shared__ unsigned short Bt[64 * KP];
  __shared__ float saL[DH], sbL[DH];
  const int tid = threadIdx.x;
  const int r0 = blockIdx.x * 128;
  if (FUSE) {
    if (tid < DH) {
      float mean = stats[tid] * invN;
      float var = stats[DH + tid] * invN - mean * mean;
      float a = rsqrtf(var + EPSV) * gam[tid];
      saL[tid] = a;
      sbL[tid] = bet[tid] - mean * a;
    }
    __syncthreads();
  }
  constexpr int KC = KP / 8;
  // stage A: one uint4 per 8-half chunk, optional BN+ReLU, XOR-swizzled store
  for (int ci = tid; ci < 128 * KC; ci += 256) {
    int row = ci / KC, kc = ci % KC, k0 = kc * 8;
    int gr = r0 + row;
    uint4 av = {0, 0, 0, 0};
    if (gr < n) av = *(const uint4*)&Aa[(size_t)gr * KP + k0];
    if (FUSE) {
      const unsigned short* ap = (const unsigned short*)&av;
      unsigned short ov[8];
#pragma unroll
      for (int j = 0; j < 8; ++j) {
        int k = k0 + j;
        float a = __half2float(__ushort_as_half(ap[j]));
        ov[j] = __half_as_ushort(__float2half(fmaxf(a * saL[k] + sbL[k], 0.f)));
      }
      av = *(uint4*)ov;
    }
    *(uint4*)&Ah[row * KP + (k0 ^ ((row & 7) * 8))] = av;
  }
  // stage B: pre-transposed fp16 wt, one uint4 per chunk
  for (int ci = tid; ci < 64 * KC; ci += 256) {
    int c = ci / KC, kc = ci % KC, k0 = kc * 8;
    uint4 wv = *(const uint4*)&wt[c * KP + k0];
    *(uint4*)&Bt[c * KP + (k0 ^ ((c & 7) * 8))] = wv;
  }
  __syncthreads();
  const int w = tid >> 6, l = tid & 63;
  const int lr = l & 15, lg = l >> 4;
  f32x4 acc[2][4];
#pragma unroll
  for (int a1 = 0; a1 < 2; ++a1)
#pragma unroll
    for (int a2 = 0; a2 < 4; ++a2) acc[a1][a2] = (f32x4){0.f, 0.f, 0.f, 0.f};
#pragma unroll
  for (int ks = 0; ks < KP / 32; ++ks) {
    const int k0 = ks * 32 + lg * 8;
    half8 av[2], bv[4];
#pragma unroll
    for (int rf = 0; rf < 2; ++rf) {
      int row = w * 32 + rf * 16 + lr;
      av[rf] = *(const half8*)&Ah[row * KP + (k0 ^ ((row & 7) * 8))];
    }
#pragma unroll
    for (int cf = 0; cf < 4; ++cf) {
      int col = cf * 16 + lr;
      bv[cf] = *(const half8*)&Bt[col * KP + (k0 ^ ((col & 7) * 8))];
    }
#pragma unroll
    for (int rf = 0; rf < 2; ++rf)
#pragma unroll
      for (int cf = 0; cf < 4; ++cf)
        acc[rf][cf] =
            __builtin_amdgcn_mfma_f32_16x16x32_f16(av[rf], bv[cf], acc[rf][cf], 0, 0, 0);
  }
  // epilogue: C/D layout col=lane&15, row=(lane>>4)*4+i
  unsigned short* Hu = (unsigned short*)Hh;
#pragma unroll
  for (int rf = 0; rf < 2; ++rf) {
#pragma unroll
    for (int cf = 0; cf < 4; ++cf) {
      int col = cf * 16 + lr;
      float bcol = bias[col];
#pragma unroll
      for (int i = 0; i < 4; ++i) {
        int row = r0 + w * 32 + rf * 16 + lg * 4 + i;
        if (row < n)
          Hu[(size_t)row * DH + col] = __half_as_ushort(__float2half(acc[rf][cf][i] + bcol));
      }
    }
  }
}

// Pull aggregation: one wave per dst row, lane d = feature d.
__global__ __launch_bounds__(256) void k_gather(
    const unsigned* __restrict__ elist, const int* __restrict__ rowstart,
    const __half* __restrict__ Hh, const float* __restrict__ sc,
    __half* __restrict__ AGGh, float* __restrict__ statp, int n) {
  const int wid = threadIdx.x >> 6;
  const int d = threadIdx.x & 63;
  const int gw = blockIdx.x * 4 + wid;
  const int nw = gridDim.x * 4;
  unsigned short* AGGu = (unsigned short*)AGGh;
  float s = 0.f, ss = 0.f;
  for (int row = gw; row < n; row += nw) {
    const int rs = rowstart[row], re = rowstart[row + 1];
    float acc = __half2float(Hh[(size_t)row * DH + d]) * sc[row];
    for (int base = rs; base < re; base += 64) {
      const int rem = re - base;
      unsigned eL = 0u;
      if (d < rem) eL = __builtin_nontemporal_load(&elist[base + d]);
      const int m = rem < 64 ? rem : 64;
      for (int j = 0; j < m; j += 8) {
#pragma unroll
        for (int jj = 0; jj < 8; ++jj) {
          const unsigned e = __shfl(eL, j + jj, 64);
          const float v = __half2float(Hh[(size_t)(e & 0x1FFFFu) * DH + d]);
          const float nm =
              __half2float(__ushort_as_half((unsigned short)(e >> 17)));
          acc = fmaf(nm, v, acc);
        }
      }
    }
    __builtin_nontemporal_store(__half_as_ushort(__float2half(acc)),
                                &AGGu[(size_t)row * DH + d]);
    s += acc;
    ss += acc * acc;
  }
  __shared__ float sm[4][DH], sm2[4][DH];
  sm[wid][d] = s;
  sm2[wid][d] = ss;
  __syncthreads();
  if (threadIdx.x < DH) {
    float a = sm[0][d] + sm[1][d] + sm[2][d] + sm[3][d];
    float b = sm2[0][d] + sm2[1][d] + sm2[2][d] + sm2[3][d];
    __builtin_nontemporal_store(a, &statp[(size_t)blockIdx.x * 128 + d]);
    __builtin_nontemporal_store(b, &statp[(size_t)blockIdx.x * 128 + DH + d]);
  }
}

// reduce per-block stat partials: one block per stat entry (128 blocks)
__global__ __launch_bounds__(256) void k_redstats(const float* __restrict__ statp,
                                                  float* __restrict__ stats, int nblk) {
  const int t = blockIdx.x;
  float s = 0.f;
  for (int b = threadIdx.x; b < nblk; b += 256) s += statp[(size_t)b * 128 + t];
#pragma unroll
  for (int o = 32; o > 0; o >>= 1) s += __shfl_down(s, o, 64);
  __shared__ float sm[4];
  if ((threadIdx.x & 63) == 0) sm[threadIdx.x >> 6] = s;
  __syncthreads();
  if (threadIdx.x == 0) stats[t] = sm[0] + sm[1] + sm[2] + sm[3];
}

// fused BN+ReLU+mean-pool+head: one block per graph.
__global__ __launch_bounds__(256) void k_poolhead(
    const __half* __restrict__ AGGh, const float* __restrict__ stats,
    const float* __restrict__ gam, const float* __restrict__ bet,
    const float* __restrict__ ow, const int* __restrict__ gstart,
    const float* __restrict__ ob, float* __restrict__ out, float invN) {
  const int g = blockIdx.x;
  const int gs = gstart[g], ge = gstart[g + 1];
  const int wid = threadIdx.x >> 6;
  const int d = threadIdx.x & 63;
  float mean = stats[d] * invN;
  float var = stats[DH + d] * invN - mean * mean;
  float sa = rsqrtf(var + EPSV) * gam[d];
  float sb = bet[d] - mean * sa;
  const float w = ow[d];
  float acc = 0.f;
  for (int row = gs + wid; row < ge; row += 4)
    acc += fmaxf(__half2float(AGGh[(size_t)row * DH + d]) * sa + sb, 0.f) * w;
#pragma unroll
  for (int off = 32; off > 0; off >>= 1) acc += __shfl_down(acc, off, 64);
  __shared__ float sm[4];
  if (d == 0) sm[wid] = acc;
  __syncthreads();
  if (threadIdx.x == 0) {
    float s = sm[0] + sm[1] + sm[2] + sm[3];
    float cnt = (float)(ge - gs);
    out[g] = s / fmaxf(cnt, 1.0f) + ob[0];
  }
}

extern "C" void kernel_launch(void* const* d_in, const int* in_sizes, int n_in,
                              void* d_out, int out_size, void* d_ws, size_t ws_size,
                              hipStream_t stream) {
  const float* x    = (const float*)d_in[0];
  const int*   ei   = (const int*)d_in[1];
  const float* ew   = (const float*)d_in[2];
  const int*   batch= (const int*)d_in[3];
  const float* w0   = (const float*)d_in[4];
  const float* b0   = (const float*)d_in[5];
  const float* g0   = (const float*)d_in[6];
  const float* be0  = (const float*)d_in[7];
  const float* w1   = (const float*)d_in[8];
  const float* b1   = (const float*)d_in[9];
  const float* g1   = (const float*)d_in[10];
  const float* be1  = (const float*)d_in[11];
  const float* w2   = (const float*)d_in[12];
  const float* b2   = (const float*)d_in[13];
  const float* g2   = (const float*)d_in[14];
  const float* be2  = (const float*)d_in[15];
  const float* ow   = (const float*)d_in[16];
  const float* ob   = (const float*)d_in[17];

  const int N_  = in_sizes[3];
  const int E_  = in_sizes[2];
  const int DIN_= in_sizes[0] / N_;
  const int G_  = out_size;
  const int* srcIdx = ei;
  const int* dstIdx = ei + E_;
  const int n1 = N_ + 1;
  const size_t epad = (size_t)E_ + 7ull * N_;

  float* ws = (float*)d_ws;
  size_t off = 0;
  unsigned long long* bstage = (unsigned long long*)(ws + off);
  off += (size_t)2 * NBUK * CAP;
  unsigned* elist = (unsigned*)(ws + off); off += epad;
  float* dinv     = ws + off; off += N_;
  float* sc       = ws + off; off += N_;
  int*   cnt      = (int*)(ws + off); off += N_;
  int*   rowstart = (int*)(ws + off); off += n1 + 1;
  int*   bsums    = (int*)(ws + off); off += 256;
  unsigned* gcur0 = (unsigned*)(ws + off); off += NBUK;
  int*   gstart   = (int*)(ws + off); off += G_ + 1;
  __half* hhalf   = (__half*)(ws + off); off += (size_t)N_ * DH / 2;
  __half* aggh    = (__half*)(ws + off); off += (size_t)N_ * DH / 2;
  unsigned short* xh = (unsigned short*)(ws + off); off += (size_t)N_ * 64;  // [N][128] fp16
  unsigned short* wt0 = (unsigned short*)(ws + off); off += 64 * 128 / 2;
  unsigned short* wt1 = (unsigned short*)(ws + off); off += 64 * 64 / 2;
  unsigned short* wt2 = (unsigned short*)(ws + off); off += 64 * 64 / 2;
  float* stats    = ws + off; off += 2 * DH;
  float* statp    = ws + off; off += (size_t)GBLK * 128;
  (void)ws_size; (void)n_in;

  // --- operand pre-conversion ---
  k_xhalf<<<(int)(((size_t)N_ * (DIN_ / 4) + 255) / 256), 256, 0, stream>>>(x, xh, N_, DIN_);
  k_wt<<<(64 * 128 + 255) / 256, 256, 0, stream>>>(w0, wt0, DIN_, 128);
  k_wt<<<(64 * 64 + 255) / 256, 256, 0, stream>>>(w1, wt1, DH, 64);
  k_wt<<<(64 * 64 + 255) / 256, 256, 0, stream>>>(w2, wt2, DH, 64);

  // --- binned CSR build ---
  k_gcur0<<<1, NBUK, 0, stream>>>(gcur0);
  k_bin0<<<(E_ + 256 * BINJ - 1) / (256 * BINJ), 256, 0, stream>>>(
      srcIdx, dstIdx, ew, gcur0, bstage, E_);
  k_bcnt<<<NBUK, 256, 0, stream>>>(bstage, gcur0, cnt, dinv, sc, N_);

  const int nb = (n1 + 1023) / 1024;
  k_scan1<<<nb, 256, 0, stream>>>(cnt, rowstart, bsums, N_, n1);
  k_scan2<<<1, 256, 0, stream>>>(bsums, nb);
  k_scan3<<<(n1 + 255) / 256, 256, 0, stream>>>(rowstart, bsums, n1);

  k_fin<<<NBUK, 256, 0, stream>>>(bstage, rowstart, gcur0, dinv, elist, N_);

  // --- graph boundaries for pooling ---
  k_gbound<<<(N_ + 255) / 256, 256, 0, stream>>>(batch, gstart, N_, G_);

  const float* Bl[3]  = {b0, b1, b2};
  const float* Gl[3]  = {g0, g1, g2};
  const float* BeL[3] = {be0, be1, be2};
  const unsigned short* Wt[3] = {wt0, wt1, wt2};

  const float invN = 1.0f / (float)N_;
  const int gblk = (N_ + 127) / 128;

  for (int l = 0; l < 3; ++l) {
    if (l == 0) {
      k_gemm_mfma<128, 0><<<gblk, 256, 0, stream>>>(
          xh, Wt[0], Bl[0], stats, nullptr, nullptr, hhalf, N_, invN);
    } else {
      k_gemm_mfma<64, 1><<<gblk, 256, 0, stream>>>(
          (const unsigned short*)aggh, Wt[l], Bl[l], stats, Gl[l - 1], BeL[l - 1],
          hhalf, N_, invN);
    }
    k_gather<<<GBLK, 256, 0, stream>>>(elist, rowstart, hhalf, sc, aggh, statp, N_);
    k_redstats<<<128, 256, 0, stream>>>(statp, stats, GBLK);
  }

  // --- fused BN2+ReLU+pooling+head ---
  k_poolhead<<<G_, 256, 0, stream>>>(aggh, stats, g2, be2, ow, gstart, ob,
                                     (float*)d_out, invN);
}